// Round 9
// baseline (827.389 us; speedup 1.0000x reference)
//
#include <hip/hip_runtime.h>
#include <hip/hip_bf16.h>
#include <math.h>

// ---------------------------------------------------------------------------
// 5x conv4d(valid)+relu -> flatten -> dense(1280->33)+relu -> dense(33->2)
// -> softmax.  B=256.
//
// R9: R8 + (a) LDS slab stride ZS=24 (48B rows, conflict-free 8-lane bank
// windows) for all MFMA convs -- R8 conv2 showed 1.06e7 SQ_LDS_BANK_CONFLICT
// from 32B-stride A-reads; (b) conv4 moved from dot2 to the MFMA template
// (dot2 issue floor ~90us vs ~23us MFMA floor): h3 becomes bf16, conv4
// emits f16 z8 h4 for conv5's dot2 path; Bq4 packed after conv2 into
// dead-h1 space (no extra workspace).
//  - conv1-4: banded-GEMM on v_mfma_f32_16x16x32_bf16 (R7-verified):
//    M=(ox,oy), N=co*16+oz, K=(ci,kx,ky)x(iz padded to ZPK), acc over kw.
//    B pre-packed in fragment order [kw][ks][nt][lane][8] (bf16 RNE).
//    A: one ds_read_b128 per fragment from ZS-strided LDS slab.
//    D: col=lane&15 (=oz), row=(lane>>4)*4+reg (=m).
//  - conv5 keeps the R3 f16 dot2 path; dense1/2 unchanged.
// ---------------------------------------------------------------------------

#define BATCH 256
typedef _Float16 half_t;
typedef _Float16 h2_t  __attribute__((ext_vector_type(2)));
typedef short    bf16x8 __attribute__((ext_vector_type(8)));
typedef float    f32x4 __attribute__((ext_vector_type(4)));
typedef unsigned int   uint32;
typedef unsigned short ushort16;

__device__ __forceinline__ float dot2f(uint32 a, uint32 b, float c) {
    return __builtin_amdgcn_fdot2(__builtin_bit_cast(h2_t, a),
                                  __builtin_bit_cast(h2_t, b), c, false);
}

// f32 -> bf16 bits, round-to-nearest-even (finite inputs only)
__device__ __forceinline__ ushort16 f2bf(float f) {
    const uint32 u = __builtin_bit_cast(uint32, f);
    return (ushort16)((u + 0x7FFFu + ((u >> 16) & 1u)) >> 16);
}

// ---- x pre-pass: fp32 [256*18][324][18] -> bf16 [256*18][324][24], pads 0
__global__ void cvt_x_pad(const float* __restrict__ x,
                          ushort16* __restrict__ xp) {
    constexpr int CH  = 972;               // uint4 chunks per (b,iw) slice
    constexpr int NSL = BATCH * 18;
    const int c = blockIdx.x * blockDim.x + threadIdx.x;
    if (c >= NSL * CH) return;
    const int s   = c / CH;
    const int j   = c - s * CH;            // chunk within slice: row r=j/3
    const int r   = j / 3;
    const int g   = j - 3 * r;             // z-phase: elems 8g..8g+8 of 24
    const float* src = x + ((size_t)s * 324 + r) * 18 + 8 * g;
    uint32 w[4];
    if (g < 2) {                           // z 0..15 all valid
        #pragma unroll
        for (int q = 0; q < 4; ++q) {
            const float2 v = ((const float2*)src)[q];   // 8B-aligned
            w[q] = (uint32)f2bf(v.x) | ((uint32)f2bf(v.y) << 16);
        }
    } else {                               // z 16,17 valid; 18..23 pad
        const float2 v = *(const float2*)src;
        w[0] = (uint32)f2bf(v.x) | ((uint32)f2bf(v.y) << 16);
        w[1] = w[2] = w[3] = 0;
    }
    ((uint4*)xp)[c] = (uint4){w[0], w[1], w[2], w[3]};
}

// ---- B-matrix pre-pack: fragment order [kw][ks][nt][lane][8], bf16 -------
template <int CIN, int COUT, int ISZ, int OSZ, int ZPK, int KS>
__device__ void pack_mfma_one(const float* __restrict__ w,
                              ushort16* __restrict__ Bq, int gtid, int gstride) {
    constexpr int TOT = 4 * KS * COUT * 512;   // 512 bf16 per fragment
    for (int t = gtid; t < TOT; t += gstride) {
        const int h  = t & 7;
        const int l  = (t >> 3) & 63;
        const int f  = t >> 9;                 // (kw*KS+ks)*COUT + nt
        const int nt = f % COUT;
        const int ks = (f / COUT) % KS;
        const int kw = f / (COUT * KS);
        const int k  = ks * 32 + (l >> 4) * 8 + h;
        const int combo = k / ZPK;
        const int iz = k - combo * ZPK;
        const int ci = combo >> 4;             // combo = (ci*4+kx)*4+ky
        const int kx = (combo >> 2) & 3;
        const int ky = combo & 3;
        const int oz = l & 15;
        const int kz = iz - oz;
        ushort16 v = 0;
        if (oz < OSZ && kz >= 0 && kz < 4 && iz < ISZ)
            v = f2bf(w[((((nt * CIN + ci) * 4 + kw) * 4 + kx) * 4 + ky) * 4 + kz]);
        Bq[t] = v;
    }
}

__global__ void pack_weights_mfma(const float* __restrict__ w1,
                                  const float* __restrict__ w2,
                                  const float* __restrict__ w3,
                                  ushort16* __restrict__ Bq1,
                                  ushort16* __restrict__ Bq2,
                                  ushort16* __restrict__ Bq3) {
    const int gtid = blockIdx.x * blockDim.x + threadIdx.x;
    const int gs   = gridDim.x * blockDim.x;
    pack_mfma_one<1, 3, 18, 15, 24, 12>(w1, Bq1, gtid, gs);
    pack_mfma_one<3, 3, 15, 12, 16, 24>(w2, Bq2, gtid, gs);
    pack_mfma_one<3, 4, 12,  9, 16, 24>(w3, Bq3, gtid, gs);
}

// conv4's fragments: packed AFTER conv2 (target space reuses dead h1)
__global__ void pack_weights_mfma4(const float* __restrict__ w4,
                                   ushort16* __restrict__ Bq4) {
    const int gtid = blockIdx.x * blockDim.x + threadIdx.x;
    const int gs   = gridDim.x * blockDim.x;
    pack_mfma_one<4, 5, 9, 6, 16, 32>(w4, Bq4, gtid, gs);
}

// ---------------------------------------------------------------------------
// MFMA conv (bf16): one (b,ow) slab per block; waves split M-tiles; each wave
// accumulates all COUT n-tiles.
//  IN_MODE 0: fp32 natural rows stride ISZ (conv1 fallback)
//  IN_MODE 2: bf16 rows pre-padded to IPZ -> uint4 staging (identity if
//             IPZ==ZS, else row-restrided)
//  OUTF16: emit f16 bits; ZS: LDS row stride (24 = 48B conflict-free);
//  OZS: output z stride (lanes with oz>=OZS skip the store).
// ---------------------------------------------------------------------------
template <int CIN, int COUT, int ISZ, int OSZ, int ZPK, int KS,
          int MT_TOT, int NT, int IN_MODE, bool OUTF16, int ZS, int IPZ, int OZS>
__global__ __launch_bounds__(NT)
void conv4d_mfma(const void* __restrict__ in_v,
                 const ushort16* __restrict__ Bq,
                 const float* __restrict__ bias,
                 ushort16* __restrict__ out) {
    constexpr int K   = 4;
    constexpr int R2  = ISZ * ISZ;
    constexpr int NW  = NT / 64;
    constexpr int MT_PER = (MT_TOT + NW - 1) / NW;
    constexpr int SLAB = (CIN * R2 + 24) * ZS;   // +24 rows OOB margin
    static_assert(CIN * 16 * ZPK == KS * 32, "K-dim bookkeeping");
    static_assert(ZPK % 8 == 0, "8-slice must not straddle combos");
    static_assert(ZS >= ZPK && IPZ >= ZPK, "strides must cover logical K rows");

    __shared__ ushort16 slab[SLAB];

    const int tid = threadIdx.x;
    const int l   = tid & 63;
    const int wv  = tid >> 6;
    const int b   = blockIdx.x / OSZ;
    const int ow  = blockIdx.x % OSZ;
    const int lg  = l >> 4;

    // NaN hardening: pads (beyond valid z) and OOB margin must be finite.
    for (int t = tid; t < SLAB; t += NT) slab[t] = 0;

    // per-lane A-row base per owned M-tile
    int mbase[MT_PER];
    #pragma unroll
    for (int i = 0; i < MT_PER; ++i) {
        const int mt = wv + NW * i;
        const int m  = (mt < MT_TOT) ? (mt * 16 + (l & 15)) : 0;
        mbase[i] = (m / OSZ) * ISZ + (m % OSZ);
    }

    f32x4 acc[MT_PER][COUT];
    #pragma unroll
    for (int i = 0; i < MT_PER; ++i)
        #pragma unroll
        for (int nt = 0; nt < COUT; ++nt)
            acc[i][nt] = (f32x4){0.f, 0.f, 0.f, 0.f};

    for (int kw = 0; kw < K; ++kw) {
        __syncthreads();                       // readers of previous slab done
        const int iw = ow + kw;
        if constexpr (IN_MODE == 0) {
            // fp32 natural, CIN==1; float2 -> packed bf16 pairs
            const float* g = (const float*)in_v +
                ((size_t)b * ISZ + iw) * (size_t)(R2 * ISZ);
            for (int t = tid; t < (R2 * ISZ) / 2; t += NT) {
                const float2 v = ((const float2*)g)[t];
                const int e = 2 * t;
                const int r = e / ISZ, z = e % ISZ;    // ISZ even: no straddle
                const uint32 pv = (uint32)f2bf(v.x) | ((uint32)f2bf(v.y) << 16);
                *(uint32*)&slab[r * ZS + z] = pv;
            }
        } else {
            constexpr int CPR = IPZ / 8;       // uint4 chunks per padded row
            constexpr int NCH = CIN * R2 * CPR;
            const ushort16* inp = (const ushort16*)in_v;
            for (int t = tid; t < NCH; t += NT) {
                const int ci  = t / (R2 * CPR);
                const int rem = t % (R2 * CPR);
                const uint4* g = (const uint4*)(inp +
                    ((size_t)(b * CIN + ci) * ISZ + iw) * (size_t)(R2 * IPZ));
                const uint4 v = g[rem];
                int dst;
                if constexpr (IPZ == ZS) {
                    dst = (ci * R2) * ZS + rem * 8;
                } else {
                    const int r = rem / CPR, c = rem % CPR;
                    dst = (ci * R2 + r) * ZS + c * 8;
                }
                *(uint4*)&slab[dst] = v;
            }
        }
        __syncthreads();

        #pragma unroll 2
        for (int ks = 0; ks < KS; ++ks) {
            // weight fragments (L2-resident, coalesced 1KB per fragment)
            bf16x8 bq[COUT];
            const ushort16* bp = Bq + (size_t)((kw * KS + ks) * COUT) * 512 + l * 8;
            #pragma unroll
            for (int nt = 0; nt < COUT; ++nt)
                bq[nt] = *(const bf16x8*)(bp + nt * 512);
            // A fragment address parts (per-lane)
            const int k8    = ks * 32 + lg * 8;
            const int combo = k8 / ZPK;
            const int iz0   = k8 - combo * ZPK;
            const int ci    = combo >> 4;
            const int kx    = (combo >> 2) & 3;
            const int ky    = combo & 3;
            const int roff  = ci * R2 + kx * ISZ + ky;
            #pragma unroll
            for (int i = 0; i < MT_PER; ++i) {
                if (wv + NW * i < MT_TOT) {
                    const bf16x8 a =
                        *(const bf16x8*)&slab[(mbase[i] + roff) * ZS + iz0];
                    #pragma unroll
                    for (int nt = 0; nt < COUT; ++nt)
                        acc[i][nt] = __builtin_amdgcn_mfma_f32_16x16x32_bf16(
                            a, bq[nt], acc[i][nt], 0, 0, 0);
                }
            }
        }
    }

    // ---- epilogue: D col = lane&15 (= oz), row = (lane>>4)*4 + reg (= m)
    const int oz = l & 15;
    #pragma unroll
    for (int i = 0; i < MT_PER; ++i) {
        const int mt = wv + NW * i;
        if (mt < MT_TOT && oz < OZS) {
            #pragma unroll
            for (int nt = 0; nt < COUT; ++nt) {
                const float bv = bias[nt];
                #pragma unroll
                for (int r = 0; r < 4; ++r) {
                    const int m = mt * 16 + (l >> 4) * 4 + r;
                    if (m < OSZ * OSZ) {
                        const int ox = m / OSZ, oy = m % OSZ;
                        const float vv = fmaxf(acc[i][nt][r] + bv, 0.f);
                        ushort16 bits;
                        if constexpr (OUTF16) {
                            const half_t hv = (half_t)vv;
                            bits = __builtin_bit_cast(ushort16, hv);
                        } else {
                            bits = f2bf(vv);
                        }
                        out[(((((size_t)b * COUT + nt) * OSZ + ow) * OSZ + ox)
                             * OSZ + oy) * OZS + oz] = bits;
                    }
                }
            }
        }
    }
}

// ---------------------------------------------------------------------------
// R3 conv path (per-(co,ox,oy) lines, LDS weights, f16 dot2) — conv5 only.
// ---------------------------------------------------------------------------
template <int CIN, int COUT, int K, int ISZ, int OSZ,
          int IPG, int OPG, int ZP, int NT, bool INF32>
__global__ __launch_bounds__(NT)
void conv4d_relu_f16(const void* __restrict__ in_v,
                     const float* __restrict__ w,
                     const float* __restrict__ bias,
                     half_t* __restrict__ out) {
    constexpr int KP  = 4;
    constexpr int R2  = ISZ * ISZ;
    constexpr int WTOT = CIN * K * K * K * COUT * KP;
    constexpr int LINES = COUT * OSZ * OSZ;
    constexpr int NIT = (LINES + NT - 1) / NT;
    constexpr int RL  = OSZ + KP - 1;
    constexpr int RQ  = (RL + 7) / 8;
    constexpr int NW  = RQ * 4;
    constexpr int NODD = (OSZ + 2) / 2;

    static_assert(8 * RQ <= ZP, "row read overruns z-pad");
    static_assert(NODD + 1 <= NW, "perm source word out of range");

    __shared__ half_t sw[WTOT];
    __shared__ half_t slab[CIN * R2 * ZP];

    const int tid = threadIdx.x;
    const int b   = blockIdx.x / OSZ;
    const int ow  = blockIdx.x % OSZ;

    for (int t = tid; t < WTOT; t += NT) {
        const int kz = t % KP; int c = t / KP;
        const int co = c % COUT; c /= COUT;
        const int ky = c % K; c /= K;
        const int kx = c % K; c /= K;
        const int kw = c % K; const int ci = c / K;
        const float v = (kz < K)
            ? w[((((co * CIN + ci) * K + kw) * K + kx) * K + ky) * K + kz]
            : 0.0f;
        sw[t] = (half_t)v;
    }

    float acc[NIT][OSZ];
    #pragma unroll
    for (int it = 0; it < NIT; ++it) {
        const int line = tid + it * NT;
        const float bv = (line < LINES) ? bias[line % COUT] : 0.0f;
        #pragma unroll
        for (int oz = 0; oz < OSZ; ++oz) acc[it][oz] = bv;
    }

    for (int kw = 0; kw < K; ++kw) {
        __syncthreads();
        const int iw = ow + kw;
        if constexpr (INF32) {
            const float* g = (const float*)in_v + ((size_t)b * ISZ + iw) * (size_t)(R2 * ISZ);
            for (int t = tid; t < R2 * ISZ; t += NT) {
                const int r = t / ISZ, z = t % ISZ;
                slab[r * ZP + z] = (half_t)g[t];
            }
        } else {
            constexpr int CPR = IPG / 8;
            constexpr int NCH = CIN * R2 * CPR;
            const half_t* inp = (const half_t*)in_v;
            for (int t = tid; t < NCH; t += NT) {
                const int ci  = t / (R2 * CPR);
                const int rem = t % (R2 * CPR);
                const int r = rem / CPR, c = rem % CPR;
                const uint4* g = (const uint4*)(inp +
                    ((size_t)(b * CIN + ci) * ISZ + iw) * (size_t)(R2 * IPG));
                const uint4 v = g[rem];
                *(uint4*)&slab[(ci * R2 + r) * ZP + 8 * c] = v;
            }
        }
        __syncthreads();

        #pragma unroll
        for (int it = 0; it < NIT; ++it) {
            const int line = tid + it * NT;
            if (line >= LINES) continue;
            const int co = line % COUT;
            const int xy = line / COUT;
            const int ox = xy / OSZ;
            const int oy = xy % OSZ;
            #pragma unroll 1
            for (int ci = 0; ci < CIN; ++ci) {
                #pragma unroll 1
                for (int kx = 0; kx < K; ++kx) {
                    #pragma unroll
                    for (int ky = 0; ky < K; ++ky) {
                        const half_t* rp = &slab[((ci * ISZ + ox + kx) * ISZ + oy + ky) * ZP];
                        uint32 wd[NW];
                        #pragma unroll
                        for (int q = 0; q < RQ; ++q) {
                            const uint4 v = ((const uint4*)rp)[q];
                            wd[4*q+0] = v.x; wd[4*q+1] = v.y;
                            wd[4*q+2] = v.z; wd[4*q+3] = v.w;
                        }
                        uint32 od[NODD];
                        #pragma unroll
                        for (int i = 0; i < NODD; ++i)
                            od[i] = __builtin_amdgcn_perm(wd[i + 1], wd[i], 0x05040302u);
                        const int wb = ((((ci * K + kw) * K + kx) * K + ky) * COUT + co) * KP;
                        const uint2 wv = *(const uint2*)&sw[wb];
                        #pragma unroll
                        for (int oz = 0; oz < OSZ; ++oz) {
                            const int s1 = oz + 2;
                            const uint32 p0 = (oz & 1) ? od[oz >> 1] : wd[oz >> 1];
                            const uint32 p1 = (s1 & 1) ? od[s1 >> 1] : wd[s1 >> 1];
                            acc[it][oz] = dot2f(p0, wv.x, dot2f(p1, wv.y, acc[it][oz]));
                        }
                    }
                }
            }
        }
    }

    #pragma unroll
    for (int it = 0; it < NIT; ++it) {
        const int line = tid + it * NT;
        if (line >= LINES) continue;
        const int co = line % COUT;
        const int xy = line / COUT;
        const int ox = xy / OSZ;
        const int oy = xy % OSZ;
        half_t* op = out + (((((size_t)b * COUT + co) * OSZ + ow) * OSZ + ox) * OSZ + oy) * OPG;
        #pragma unroll
        for (int p = 0; p < OSZ / 2; ++p) {
            h2_t pv = { (half_t)fmaxf(acc[it][2*p],     0.0f),
                        (half_t)fmaxf(acc[it][2*p + 1], 0.0f) };
            ((uint32*)op)[p] = __builtin_bit_cast(uint32, pv);
        }
        if constexpr (OSZ & 1)
            op[OSZ - 1] = (half_t)fmaxf(acc[it][OSZ - 1], 0.0f);
    }
}

// dense1: out[b,j] = relu(sum_k h[b,k]*w[j,k] + bias[j]); h f16 [256,1280]
__global__ void dense1_relu_f16(const half_t* __restrict__ h,
                                const float* __restrict__ w,
                                const float* __restrict__ bias,
                                float* __restrict__ out) {
    int idx = blockIdx.x * blockDim.x + threadIdx.x;
    if (idx >= BATCH * 33) return;
    const int j = idx % 33;
    const int i = idx / 33;
    const half_t* hr = h + (size_t)i * 1280;
    const float*  wr = w + (size_t)j * 1280;
    float a0 = bias[j], a1 = 0.f, a2 = 0.f, a3 = 0.f;
    for (int k = 0; k < 1280; k += 4) {
        a0 = fmaf((float)hr[k + 0], wr[k + 0], a0);
        a1 = fmaf((float)hr[k + 1], wr[k + 1], a1);
        a2 = fmaf((float)hr[k + 2], wr[k + 2], a2);
        a3 = fmaf((float)hr[k + 3], wr[k + 3], a3);
    }
    out[idx] = fmaxf((a0 + a1) + (a2 + a3), 0.0f);
}

// dense2 + softmax over 2 classes. h:[256,33] fp32, w:[2,33], out:[256,2]
__global__ void dense2_softmax(const float* __restrict__ h,
                               const float* __restrict__ w,
                               const float* __restrict__ bias,
                               float* __restrict__ out) {
    int i = blockIdx.x * blockDim.x + threadIdx.x;
    if (i >= BATCH) return;
    const float* hr = h + (size_t)i * 33;
    float a0 = bias[0], a1 = bias[1];
    for (int k = 0; k < 33; ++k) {
        a0 = fmaf(hr[k], w[k], a0);
        a1 = fmaf(hr[k], w[33 + k], a1);
    }
    const float m = fmaxf(a0, a1);
    const float e0 = expf(a0 - m);
    const float e1 = expf(a1 - m);
    const float s = e0 + e1;
    out[i * 2 + 0] = e0 / s;
    out[i * 2 + 1] = e1 / s;
}

extern "C" void kernel_launch(void* const* d_in, const int* in_sizes, int n_in,
                              void* d_out, int out_size, void* d_ws, size_t ws_size,
                              hipStream_t stream) {
    const float* x   = (const float*)d_in[0];
    const float* w1  = (const float*)d_in[1];
    const float* b1  = (const float*)d_in[2];
    const float* w2  = (const float*)d_in[3];
    const float* b2  = (const float*)d_in[4];
    const float* w3  = (const float*)d_in[5];
    const float* b3  = (const float*)d_in[6];
    const float* w4  = (const float*)d_in[7];
    const float* b4  = (const float*)d_in[8];
    const float* w5  = (const float*)d_in[9];
    const float* b5  = (const float*)d_in[10];
    const float* dw1 = (const float*)d_in[11];
    const float* db1 = (const float*)d_in[12];
    const float* dw2 = (const float*)d_in[13];
    const float* db2 = (const float*)d_in[14];

    // Workspace (16-bit units). Region A at 0, region B at 42M (84 MB).
    //  A: h1 bf16 41.472M / h3(bf16 z16, 11.94M) / h5(f16 0.33M);
    //     Bq1..Bq3 at A+41.5M; Bq4 at A+30M (packed AFTER conv2, h1 dead,
    //     above h3, below Bq1..3; read by conv4 before conv5 writes h5)
    //  B: xp bf16 35.83M (dead after conv1) / h2 bf16 21.23M / h4(f16 z8)
    //     / h6(fp32 at +8M ushort16-units; h2 dead by then)
    ushort16* wsA = (ushort16*)d_ws;
    ushort16* wsB = wsA + 42000000;

    ushort16* h1 = wsA;               // bf16, padded z=16
    ushort16* xp = wsB;               // bf16, padded z=24 (35,831,808)
    ushort16* h2 = wsB;               // bf16, padded z=16 (after xp dead)
    ushort16* h3 = wsA;               // bf16, padded z=16
    half_t*   h4 = (half_t*)wsB;      // f16, padded z=8
    half_t*   h5 = (half_t*)wsA;      // f16, natural [256][1280]
    float*    h6 = (float*)(wsB + 8000000);
    ushort16* Bq1 = wsA + 41500000;   // 4*12*3*512 = 73,728
    ushort16* Bq2 = wsA + 41600000;   // 4*24*3*512 = 147,456
    ushort16* Bq3 = wsA + 41760000;   // 4*24*4*512 = 196,608
    ushort16* Bq4 = wsA + 30000000;   // 4*32*5*512 = 327,680 (dead-h1 space)
    float* outp = (float*)d_out;

    // primary layout needs (42,000,000 + 35,831,808) * 2 bytes
    const bool big_ws = ws_size >= (size_t)155663616ull;

    // weight fragment pre-pack for conv1-3
    hipLaunchKernelGGL(pack_weights_mfma, dim3(64), dim3(256), 0, stream,
                       w1, w2, w3, Bq1, Bq2, Bq3);

    if (big_ws) {
        // x fp32 -> bf16 pre-padded [b][iw][324][24]
        constexpr int NCH = BATCH * 18 * 972;
        hipLaunchKernelGGL(cvt_x_pad, dim3((NCH + 255) / 256), dim3(256),
                           0, stream, x, xp);
        // conv1 from xp: identity-copy staging (IN_MODE 2, IPZ==ZS==24)
        hipLaunchKernelGGL((conv4d_mfma<1, 3, 18, 15, 24, 12, 15, 256, 2, false, 24, 24, 16>),
                           dim3(BATCH * 15), dim3(256), 0, stream, xp, Bq1, b1, h1);
    } else {
        // fallback: fp32 staging (IN_MODE 0)
        hipLaunchKernelGGL((conv4d_mfma<1, 3, 18, 15, 24, 12, 15, 256, 0, false, 24, 24, 16>),
                           dim3(BATCH * 15), dim3(256), 0, stream, x, Bq1, b1, h1);
    }
    // conv2: h1 -> h2 (bf16).  M=144 (9 Mt), ZPK=16, ZS=24, KS=24.
    hipLaunchKernelGGL((conv4d_mfma<3, 3, 15, 12, 16, 24, 9, 256, 2, false, 24, 16, 16>),
                       dim3(BATCH * 12), dim3(256), 0, stream, h1, Bq2, b2, h2);
    // conv4 fragment pack (h1 dead now; Bq4 lives in its space)
    hipLaunchKernelGGL(pack_weights_mfma4, dim3(64), dim3(256), 0, stream,
                       w4, Bq4);
    // conv3: h2 -> h3 (bf16 for conv4-MFMA).  M=81 (6 Mt), ZPK=16, KS=24.
    hipLaunchKernelGGL((conv4d_mfma<3, 4, 12, 9, 16, 24, 6, 256, 2, false, 24, 16, 16>),
                       dim3(BATCH * 9), dim3(256), 0, stream, h2, Bq3, b3, h3);
    // conv4: h3 -> h4 (f16 z8 for conv5's dot2).  M=36 (3 Mt), ZPK=16, KS=32.
    hipLaunchKernelGGL((conv4d_mfma<4, 5, 9, 6, 16, 32, 3, 192, 2, true, 24, 16, 8>),
                       dim3(BATCH * 6), dim3(192), 0, stream, h3, Bq4, b4,
                       (ushort16*)h4);
    // conv5: h4 -> h5 (natural, z=4);  R3 f16 dot2 path
    hipLaunchKernelGGL((conv4d_relu_f16<5, 5, 3, 6, 4, 8, 4, 8, 128, false>),
                       dim3(BATCH * 4), dim3(128), 0, stream, h4, w5, b5, h5);
    {   // dense1
        dim3 grid((BATCH * 33 + 255) / 256);
        hipLaunchKernelGGL(dense1_relu_f16, grid, dim3(256), 0, stream, h5, dw1, db1, h6);
    }
    {   // dense2 + softmax
        hipLaunchKernelGGL(dense2_softmax, dim3(1), dim3(256), 0, stream,
                           h6, dw2, db2, outp);
    }
}

// Round 10
// 807.621 us; speedup vs baseline: 1.0245x; 1.0245x over previous
//
#include <hip/hip_runtime.h>
#include <hip/hip_bf16.h>
#include <math.h>

// ---------------------------------------------------------------------------
// 5x conv4d(valid)+relu -> flatten -> dense(1280->33)+relu -> dense(33->2)
// -> softmax.  B=256.
//
// R10: R8 config restored (ZS=16 slabs, conv4 on dot2) + NT 256->128 on the
// MFMA convs.  R9 post-mortem: (a) ZS=24 made bank conflicts WORSE (2.3e7 vs
// 1.1e7) -- reverted; (b) conv4-MFMA streams 2.9GB of B-fragments from L2
// (each wave re-reads all fragments) -- reverted to dot2.  The dominant
// non-MFMA term in conv1-3 is that same per-wave Bq streaming (conv2:
// 4 waves x 288KB x 3072 blocks = 3.5GB ~ 56% of L2 BW).  NT=128 halves
// waves/block -> each fragment read feeds ~2x M-tiles -> Bq traffic /2.
//  - conv1-3: banded-GEMM on v_mfma_f32_16x16x32_bf16 (R7-verified):
//    M=(ox,oy), N=co*16+oz, K=(ci,kx,ky)x(iz padded to ZPK), acc over kw.
//    B pre-packed in fragment order [kw][ks][nt][lane][8] (bf16 RNE).
//    A: one ds_read_b128 per fragment from ZS-strided LDS slab.
//    D: col=lane&15 (=oz), row=(lane>>4)*4+reg (=m).
//  - conv4/5 on the R3 f16 dot2 path; dense1/2 unchanged.
// ---------------------------------------------------------------------------

#define BATCH 256
typedef _Float16 half_t;
typedef _Float16 h2_t  __attribute__((ext_vector_type(2)));
typedef short    bf16x8 __attribute__((ext_vector_type(8)));
typedef float    f32x4 __attribute__((ext_vector_type(4)));
typedef unsigned int   uint32;
typedef unsigned short ushort16;

__device__ __forceinline__ float dot2f(uint32 a, uint32 b, float c) {
    return __builtin_amdgcn_fdot2(__builtin_bit_cast(h2_t, a),
                                  __builtin_bit_cast(h2_t, b), c, false);
}

// f32 -> bf16 bits, round-to-nearest-even (finite inputs only)
__device__ __forceinline__ ushort16 f2bf(float f) {
    const uint32 u = __builtin_bit_cast(uint32, f);
    return (ushort16)((u + 0x7FFFu + ((u >> 16) & 1u)) >> 16);
}

// ---- x pre-pass: fp32 [256*18][324][18] -> bf16 [256*18][324][24], pads 0
__global__ void cvt_x_pad(const float* __restrict__ x,
                          ushort16* __restrict__ xp) {
    constexpr int CH  = 972;               // uint4 chunks per (b,iw) slice
    constexpr int NSL = BATCH * 18;
    const int c = blockIdx.x * blockDim.x + threadIdx.x;
    if (c >= NSL * CH) return;
    const int s   = c / CH;
    const int j   = c - s * CH;            // chunk within slice: row r=j/3
    const int r   = j / 3;
    const int g   = j - 3 * r;             // z-phase: elems 8g..8g+8 of 24
    const float* src = x + ((size_t)s * 324 + r) * 18 + 8 * g;
    uint32 w[4];
    if (g < 2) {                           // z 0..15 all valid
        #pragma unroll
        for (int q = 0; q < 4; ++q) {
            const float2 v = ((const float2*)src)[q];   // 8B-aligned
            w[q] = (uint32)f2bf(v.x) | ((uint32)f2bf(v.y) << 16);
        }
    } else {                               // z 16,17 valid; 18..23 pad
        const float2 v = *(const float2*)src;
        w[0] = (uint32)f2bf(v.x) | ((uint32)f2bf(v.y) << 16);
        w[1] = w[2] = w[3] = 0;
    }
    ((uint4*)xp)[c] = (uint4){w[0], w[1], w[2], w[3]};
}

// ---- B-matrix pre-pack: fragment order [kw][ks][nt][lane][8], bf16 -------
template <int CIN, int COUT, int ISZ, int OSZ, int ZPK, int KS>
__device__ void pack_mfma_one(const float* __restrict__ w,
                              ushort16* __restrict__ Bq, int gtid, int gstride) {
    constexpr int TOT = 4 * KS * COUT * 512;   // 512 bf16 per fragment
    for (int t = gtid; t < TOT; t += gstride) {
        const int h  = t & 7;
        const int l  = (t >> 3) & 63;
        const int f  = t >> 9;                 // (kw*KS+ks)*COUT + nt
        const int nt = f % COUT;
        const int ks = (f / COUT) % KS;
        const int kw = f / (COUT * KS);
        const int k  = ks * 32 + (l >> 4) * 8 + h;
        const int combo = k / ZPK;
        const int iz = k - combo * ZPK;
        const int ci = combo >> 4;             // combo = (ci*4+kx)*4+ky
        const int kx = (combo >> 2) & 3;
        const int ky = combo & 3;
        const int oz = l & 15;
        const int kz = iz - oz;
        ushort16 v = 0;
        if (oz < OSZ && kz >= 0 && kz < 4 && iz < ISZ)
            v = f2bf(w[((((nt * CIN + ci) * 4 + kw) * 4 + kx) * 4 + ky) * 4 + kz]);
        Bq[t] = v;
    }
}

__global__ void pack_weights_mfma(const float* __restrict__ w1,
                                  const float* __restrict__ w2,
                                  const float* __restrict__ w3,
                                  ushort16* __restrict__ Bq1,
                                  ushort16* __restrict__ Bq2,
                                  ushort16* __restrict__ Bq3) {
    const int gtid = blockIdx.x * blockDim.x + threadIdx.x;
    const int gs   = gridDim.x * blockDim.x;
    pack_mfma_one<1, 3, 18, 15, 24, 12>(w1, Bq1, gtid, gs);
    pack_mfma_one<3, 3, 15, 12, 16, 24>(w2, Bq2, gtid, gs);
    pack_mfma_one<3, 4, 12,  9, 16, 24>(w3, Bq3, gtid, gs);
}

// ---------------------------------------------------------------------------
// MFMA conv (bf16): one (b,ow) slab per block; waves split M-tiles; each wave
// accumulates all COUT n-tiles.
//  IN_MODE 0: fp32 natural rows stride ISZ (conv1 fallback)
//  IN_MODE 2: bf16 rows pre-padded to IPZ -> uint4 staging (identity if
//             IPZ==ZS, else row-restrided)
//  OUTF16: emit f16 bits; ZS: LDS row stride; OZS: output z stride.
// ---------------------------------------------------------------------------
template <int CIN, int COUT, int ISZ, int OSZ, int ZPK, int KS,
          int MT_TOT, int NT, int IN_MODE, bool OUTF16, int ZS, int IPZ, int OZS>
__global__ __launch_bounds__(NT)
void conv4d_mfma(const void* __restrict__ in_v,
                 const ushort16* __restrict__ Bq,
                 const float* __restrict__ bias,
                 ushort16* __restrict__ out) {
    constexpr int K   = 4;
    constexpr int R2  = ISZ * ISZ;
    constexpr int NW  = NT / 64;
    constexpr int MT_PER = (MT_TOT + NW - 1) / NW;
    constexpr int SLAB = (CIN * R2 + 24) * ZS;   // +24 rows OOB margin
    static_assert(CIN * 16 * ZPK == KS * 32, "K-dim bookkeeping");
    static_assert(ZPK % 8 == 0, "8-slice must not straddle combos");
    static_assert(ZS >= ZPK && IPZ >= ZPK, "strides must cover logical K rows");

    __shared__ ushort16 slab[SLAB];

    const int tid = threadIdx.x;
    const int l   = tid & 63;
    const int wv  = tid >> 6;
    const int b   = blockIdx.x / OSZ;
    const int ow  = blockIdx.x % OSZ;
    const int lg  = l >> 4;

    // NaN hardening: pads (beyond valid z) and OOB margin must be finite.
    for (int t = tid; t < SLAB; t += NT) slab[t] = 0;

    // per-lane A-row base per owned M-tile
    int mbase[MT_PER];
    #pragma unroll
    for (int i = 0; i < MT_PER; ++i) {
        const int mt = wv + NW * i;
        const int m  = (mt < MT_TOT) ? (mt * 16 + (l & 15)) : 0;
        mbase[i] = (m / OSZ) * ISZ + (m % OSZ);
    }

    f32x4 acc[MT_PER][COUT];
    #pragma unroll
    for (int i = 0; i < MT_PER; ++i)
        #pragma unroll
        for (int nt = 0; nt < COUT; ++nt)
            acc[i][nt] = (f32x4){0.f, 0.f, 0.f, 0.f};

    for (int kw = 0; kw < K; ++kw) {
        __syncthreads();                       // readers of previous slab done
        const int iw = ow + kw;
        if constexpr (IN_MODE == 0) {
            // fp32 natural, CIN==1; float2 -> packed bf16 pairs
            const float* g = (const float*)in_v +
                ((size_t)b * ISZ + iw) * (size_t)(R2 * ISZ);
            for (int t = tid; t < (R2 * ISZ) / 2; t += NT) {
                const float2 v = ((const float2*)g)[t];
                const int e = 2 * t;
                const int r = e / ISZ, z = e % ISZ;    // ISZ even: no straddle
                const uint32 pv = (uint32)f2bf(v.x) | ((uint32)f2bf(v.y) << 16);
                *(uint32*)&slab[r * ZS + z] = pv;
            }
        } else {
            constexpr int CPR = IPZ / 8;       // uint4 chunks per padded row
            constexpr int NCH = CIN * R2 * CPR;
            const ushort16* inp = (const ushort16*)in_v;
            for (int t = tid; t < NCH; t += NT) {
                const int ci  = t / (R2 * CPR);
                const int rem = t % (R2 * CPR);
                const uint4* g = (const uint4*)(inp +
                    ((size_t)(b * CIN + ci) * ISZ + iw) * (size_t)(R2 * IPZ));
                const uint4 v = g[rem];
                int dst;
                if constexpr (IPZ == ZS) {
                    dst = (ci * R2) * ZS + rem * 8;
                } else {
                    const int r = rem / CPR, c = rem % CPR;
                    dst = (ci * R2 + r) * ZS + c * 8;
                }
                *(uint4*)&slab[dst] = v;
            }
        }
        __syncthreads();

        #pragma unroll 2
        for (int ks = 0; ks < KS; ++ks) {
            // weight fragments (L2-resident, coalesced 1KB per fragment)
            bf16x8 bq[COUT];
            const ushort16* bp = Bq + (size_t)((kw * KS + ks) * COUT) * 512 + l * 8;
            #pragma unroll
            for (int nt = 0; nt < COUT; ++nt)
                bq[nt] = *(const bf16x8*)(bp + nt * 512);
            // A fragment address parts (per-lane)
            const int k8    = ks * 32 + lg * 8;
            const int combo = k8 / ZPK;
            const int iz0   = k8 - combo * ZPK;
            const int ci    = combo >> 4;
            const int kx    = (combo >> 2) & 3;
            const int ky    = combo & 3;
            const int roff  = ci * R2 + kx * ISZ + ky;
            #pragma unroll
            for (int i = 0; i < MT_PER; ++i) {
                if (wv + NW * i < MT_TOT) {
                    const bf16x8 a =
                        *(const bf16x8*)&slab[(mbase[i] + roff) * ZS + iz0];
                    #pragma unroll
                    for (int nt = 0; nt < COUT; ++nt)
                        acc[i][nt] = __builtin_amdgcn_mfma_f32_16x16x32_bf16(
                            a, bq[nt], acc[i][nt], 0, 0, 0);
                }
            }
        }
    }

    // ---- epilogue: D col = lane&15 (= oz), row = (lane>>4)*4 + reg (= m)
    const int oz = l & 15;
    #pragma unroll
    for (int i = 0; i < MT_PER; ++i) {
        const int mt = wv + NW * i;
        if (mt < MT_TOT && oz < OZS) {
            #pragma unroll
            for (int nt = 0; nt < COUT; ++nt) {
                const float bv = bias[nt];
                #pragma unroll
                for (int r = 0; r < 4; ++r) {
                    const int m = mt * 16 + (l >> 4) * 4 + r;
                    if (m < OSZ * OSZ) {
                        const int ox = m / OSZ, oy = m % OSZ;
                        const float vv = fmaxf(acc[i][nt][r] + bv, 0.f);
                        ushort16 bits;
                        if constexpr (OUTF16) {
                            const half_t hv = (half_t)vv;
                            bits = __builtin_bit_cast(ushort16, hv);
                        } else {
                            bits = f2bf(vv);
                        }
                        out[(((((size_t)b * COUT + nt) * OSZ + ow) * OSZ + ox)
                             * OSZ + oy) * OZS + oz] = bits;
                    }
                }
            }
        }
    }
}

// ---------------------------------------------------------------------------
// R3 conv path (per-(co,ox,oy) lines, LDS weights, f16 dot2) — conv4/conv5.
// ---------------------------------------------------------------------------
template <int CIN, int COUT, int K, int ISZ, int OSZ,
          int IPG, int OPG, int ZP, int NT, bool INF32>
__global__ __launch_bounds__(NT)
void conv4d_relu_f16(const void* __restrict__ in_v,
                     const float* __restrict__ w,
                     const float* __restrict__ bias,
                     half_t* __restrict__ out) {
    constexpr int KP  = 4;
    constexpr int R2  = ISZ * ISZ;
    constexpr int WTOT = CIN * K * K * K * COUT * KP;
    constexpr int LINES = COUT * OSZ * OSZ;
    constexpr int NIT = (LINES + NT - 1) / NT;
    constexpr int RL  = OSZ + KP - 1;
    constexpr int RQ  = (RL + 7) / 8;
    constexpr int NW  = RQ * 4;
    constexpr int NODD = (OSZ + 2) / 2;

    static_assert(8 * RQ <= ZP, "row read overruns z-pad");
    static_assert(NODD + 1 <= NW, "perm source word out of range");

    __shared__ half_t sw[WTOT];
    __shared__ half_t slab[CIN * R2 * ZP];

    const int tid = threadIdx.x;
    const int b   = blockIdx.x / OSZ;
    const int ow  = blockIdx.x % OSZ;

    for (int t = tid; t < WTOT; t += NT) {
        const int kz = t % KP; int c = t / KP;
        const int co = c % COUT; c /= COUT;
        const int ky = c % K; c /= K;
        const int kx = c % K; c /= K;
        const int kw = c % K; const int ci = c / K;
        const float v = (kz < K)
            ? w[((((co * CIN + ci) * K + kw) * K + kx) * K + ky) * K + kz]
            : 0.0f;
        sw[t] = (half_t)v;
    }

    float acc[NIT][OSZ];
    #pragma unroll
    for (int it = 0; it < NIT; ++it) {
        const int line = tid + it * NT;
        const float bv = (line < LINES) ? bias[line % COUT] : 0.0f;
        #pragma unroll
        for (int oz = 0; oz < OSZ; ++oz) acc[it][oz] = bv;
    }

    for (int kw = 0; kw < K; ++kw) {
        __syncthreads();
        const int iw = ow + kw;
        if constexpr (INF32) {
            const float* g = (const float*)in_v + ((size_t)b * ISZ + iw) * (size_t)(R2 * ISZ);
            for (int t = tid; t < R2 * ISZ; t += NT) {
                const int r = t / ISZ, z = t % ISZ;
                slab[r * ZP + z] = (half_t)g[t];
            }
        } else {
            constexpr int CPR = IPG / 8;
            constexpr int NCH = CIN * R2 * CPR;
            const half_t* inp = (const half_t*)in_v;
            for (int t = tid; t < NCH; t += NT) {
                const int ci  = t / (R2 * CPR);
                const int rem = t % (R2 * CPR);
                const int r = rem / CPR, c = rem % CPR;
                const uint4* g = (const uint4*)(inp +
                    ((size_t)(b * CIN + ci) * ISZ + iw) * (size_t)(R2 * IPG));
                const uint4 v = g[rem];
                *(uint4*)&slab[(ci * R2 + r) * ZP + 8 * c] = v;
            }
        }
        __syncthreads();

        #pragma unroll
        for (int it = 0; it < NIT; ++it) {
            const int line = tid + it * NT;
            if (line >= LINES) continue;
            const int co = line % COUT;
            const int xy = line / COUT;
            const int ox = xy / OSZ;
            const int oy = xy % OSZ;
            #pragma unroll 1
            for (int ci = 0; ci < CIN; ++ci) {
                #pragma unroll 1
                for (int kx = 0; kx < K; ++kx) {
                    #pragma unroll
                    for (int ky = 0; ky < K; ++ky) {
                        const half_t* rp = &slab[((ci * ISZ + ox + kx) * ISZ + oy + ky) * ZP];
                        uint32 wd[NW];
                        #pragma unroll
                        for (int q = 0; q < RQ; ++q) {
                            const uint4 v = ((const uint4*)rp)[q];
                            wd[4*q+0] = v.x; wd[4*q+1] = v.y;
                            wd[4*q+2] = v.z; wd[4*q+3] = v.w;
                        }
                        uint32 od[NODD];
                        #pragma unroll
                        for (int i = 0; i < NODD; ++i)
                            od[i] = __builtin_amdgcn_perm(wd[i + 1], wd[i], 0x05040302u);
                        const int wb = ((((ci * K + kw) * K + kx) * K + ky) * COUT + co) * KP;
                        const uint2 wv = *(const uint2*)&sw[wb];
                        #pragma unroll
                        for (int oz = 0; oz < OSZ; ++oz) {
                            const int s1 = oz + 2;
                            const uint32 p0 = (oz & 1) ? od[oz >> 1] : wd[oz >> 1];
                            const uint32 p1 = (s1 & 1) ? od[s1 >> 1] : wd[s1 >> 1];
                            acc[it][oz] = dot2f(p0, wv.x, dot2f(p1, wv.y, acc[it][oz]));
                        }
                    }
                }
            }
        }
    }

    #pragma unroll
    for (int it = 0; it < NIT; ++it) {
        const int line = tid + it * NT;
        if (line >= LINES) continue;
        const int co = line % COUT;
        const int xy = line / COUT;
        const int ox = xy / OSZ;
        const int oy = xy % OSZ;
        half_t* op = out + (((((size_t)b * COUT + co) * OSZ + ow) * OSZ + ox) * OSZ + oy) * OPG;
        #pragma unroll
        for (int p = 0; p < OSZ / 2; ++p) {
            h2_t pv = { (half_t)fmaxf(acc[it][2*p],     0.0f),
                        (half_t)fmaxf(acc[it][2*p + 1], 0.0f) };
            ((uint32*)op)[p] = __builtin_bit_cast(uint32, pv);
        }
        if constexpr (OSZ & 1)
            op[OSZ - 1] = (half_t)fmaxf(acc[it][OSZ - 1], 0.0f);
    }
}

// dense1: out[b,j] = relu(sum_k h[b,k]*w[j,k] + bias[j]); h f16 [256,1280]
__global__ void dense1_relu_f16(const half_t* __restrict__ h,
                                const float* __restrict__ w,
                                const float* __restrict__ bias,
                                float* __restrict__ out) {
    int idx = blockIdx.x * blockDim.x + threadIdx.x;
    if (idx >= BATCH * 33) return;
    const int j = idx % 33;
    const int i = idx / 33;
    const half_t* hr = h + (size_t)i * 1280;
    const float*  wr = w + (size_t)j * 1280;
    float a0 = bias[j], a1 = 0.f, a2 = 0.f, a3 = 0.f;
    for (int k = 0; k < 1280; k += 4) {
        a0 = fmaf((float)hr[k + 0], wr[k + 0], a0);
        a1 = fmaf((float)hr[k + 1], wr[k + 1], a1);
        a2 = fmaf((float)hr[k + 2], wr[k + 2], a2);
        a3 = fmaf((float)hr[k + 3], wr[k + 3], a3);
    }
    out[idx] = fmaxf((a0 + a1) + (a2 + a3), 0.0f);
}

// dense2 + softmax over 2 classes. h:[256,33] fp32, w:[2,33], out:[256,2]
__global__ void dense2_softmax(const float* __restrict__ h,
                               const float* __restrict__ w,
                               const float* __restrict__ bias,
                               float* __restrict__ out) {
    int i = blockIdx.x * blockDim.x + threadIdx.x;
    if (i >= BATCH) return;
    const float* hr = h + (size_t)i * 33;
    float a0 = bias[0], a1 = bias[1];
    for (int k = 0; k < 33; ++k) {
        a0 = fmaf(hr[k], w[k], a0);
        a1 = fmaf(hr[k], w[33 + k], a1);
    }
    const float m = fmaxf(a0, a1);
    const float e0 = expf(a0 - m);
    const float e1 = expf(a1 - m);
    const float s = e0 + e1;
    out[i * 2 + 0] = e0 / s;
    out[i * 2 + 1] = e1 / s;
}

extern "C" void kernel_launch(void* const* d_in, const int* in_sizes, int n_in,
                              void* d_out, int out_size, void* d_ws, size_t ws_size,
                              hipStream_t stream) {
    const float* x   = (const float*)d_in[0];
    const float* w1  = (const float*)d_in[1];
    const float* b1  = (const float*)d_in[2];
    const float* w2  = (const float*)d_in[3];
    const float* b2  = (const float*)d_in[4];
    const float* w3  = (const float*)d_in[5];
    const float* b3  = (const float*)d_in[6];
    const float* w4  = (const float*)d_in[7];
    const float* b4  = (const float*)d_in[8];
    const float* w5  = (const float*)d_in[9];
    const float* b5  = (const float*)d_in[10];
    const float* dw1 = (const float*)d_in[11];
    const float* db1 = (const float*)d_in[12];
    const float* dw2 = (const float*)d_in[13];
    const float* db2 = (const float*)d_in[14];

    // Workspace (16-bit units). Region A at 0, region B at 42M (84 MB).
    //  A: h1 bf16 41.472M / h3(f16 z16) / h5(f16); Bq1..Bq3 at A+41.5M
    //  B: xp bf16 35.83M (dead after conv1) / h2 bf16 21.23M / h4(f16 z8)
    //     / h6(fp32 at +8M ushort16-units)
    ushort16* wsA = (ushort16*)d_ws;
    ushort16* wsB = wsA + 42000000;

    ushort16* h1 = wsA;               // bf16, padded z=16
    ushort16* xp = wsB;               // bf16, padded z=24 (35,831,808)
    ushort16* h2 = wsB;               // bf16, padded z=16 (after xp dead)
    ushort16* h3 = wsA;               // f16 bits, padded z=16
    half_t*   h4 = (half_t*)wsB;      // f16, padded z=8
    half_t*   h5 = (half_t*)wsA;      // f16, natural [256][1280]
    float*    h6 = (float*)(wsB + 8000000);
    ushort16* Bq1 = wsA + 41500000;   // 4*12*3*512 = 73,728
    ushort16* Bq2 = wsA + 41600000;   // 4*24*3*512 = 147,456
    ushort16* Bq3 = wsA + 41760000;   // 4*24*4*512 = 196,608
    float* outp = (float*)d_out;

    // primary layout needs (42,000,000 + 35,831,808) * 2 bytes
    const bool big_ws = ws_size >= (size_t)155663616ull;

    // weight fragment pre-pack for conv1-3
    hipLaunchKernelGGL(pack_weights_mfma, dim3(64), dim3(256), 0, stream,
                       w1, w2, w3, Bq1, Bq2, Bq3);

    if (big_ws) {
        // x fp32 -> bf16 pre-padded [b][iw][324][24]
        constexpr int NCH = BATCH * 18 * 972;
        hipLaunchKernelGGL(cvt_x_pad, dim3((NCH + 255) / 256), dim3(256),
                           0, stream, x, xp);
        // conv1 from xp: identity-copy staging (IN_MODE 2, IPZ==ZS==24)
        hipLaunchKernelGGL((conv4d_mfma<1, 3, 18, 15, 24, 12, 15, 128, 2, false, 24, 24, 16>),
                           dim3(BATCH * 15), dim3(128), 0, stream, xp, Bq1, b1, h1);
    } else {
        // fallback: fp32 staging (IN_MODE 0)
        hipLaunchKernelGGL((conv4d_mfma<1, 3, 18, 15, 24, 12, 15, 128, 0, false, 24, 24, 16>),
                           dim3(BATCH * 15), dim3(128), 0, stream, x, Bq1, b1, h1);
    }
    // conv2: h1 -> h2 (bf16).  M=144 (9 Mt), ZPK=ZS=16, KS=24, 2 waves.
    hipLaunchKernelGGL((conv4d_mfma<3, 3, 15, 12, 16, 24, 9, 128, 2, false, 16, 16, 16>),
                       dim3(BATCH * 12), dim3(128), 0, stream, h1, Bq2, b2, h2);
    // conv3: h2 -> h3 (f16 out for conv4).  M=81 (6 Mt), ZPK=ZS=16, KS=24.
    hipLaunchKernelGGL((conv4d_mfma<3, 4, 12, 9, 16, 24, 6, 128, 2, true, 16, 16, 16>),
                       dim3(BATCH * 9), dim3(128), 0, stream, h2, Bq3, b3, h3);
    // conv4: h3 -> h4;  R3 f16 dot2 path
    hipLaunchKernelGGL((conv4d_relu_f16<4, 5, 4, 9, 6, 16, 8, 24, 192, false>),
                       dim3(BATCH * 6), dim3(192), 0, stream, h3, w4, b4, h4);
    // conv5: h4 -> h5 (natural, z=4);  R3 f16 dot2 path
    hipLaunchKernelGGL((conv4d_relu_f16<5, 5, 3, 6, 4, 8, 4, 8, 128, false>),
                       dim3(BATCH * 4), dim3(128), 0, stream, h4, w5, b5, h5);
    {   // dense1
        dim3 grid((BATCH * 33 + 255) / 256);
        hipLaunchKernelGGL(dense1_relu_f16, grid, dim3(256), 0, stream, h5, dw1, db1, h6);
    }
    {   // dense2 + softmax
        hipLaunchKernelGGL(dense2_softmax, dim3(1), dim3(256), 0, stream,
                           h6, dw2, db2, outp);
    }
}

// Round 11
// 719.208 us; speedup vs baseline: 1.1504x; 1.1229x over previous
//
#include <hip/hip_runtime.h>
#include <hip/hip_bf16.h>
#include <math.h>

// ---------------------------------------------------------------------------
// 5x conv4d(valid)+relu -> flatten -> dense(1280->33)+relu -> dense(33->2)
// -> softmax.  B=256.
//
// R11: R8 config restored exactly (NT=256, ZS: conv1=24, conv2/3=16, conv4/5
// on dot2) + depth-1 register prefetch of B-fragments in the MFMA convs.
//  R10 post-mortem: NT=128 -> MT_PER 8 -> VGPR 104 -> occupancy 21.7% ->
//  conv1 224us. Reverted.  R8 conv2 model: 3 Bq global loads (L2 ~200cyc)
//  feed the SAME iteration's 9 MFMAs (44cyc) -> ~40% per-wave MFMA duty x
//  3.75 waves/SIMD ~= the observed 31% MfmaUtil.  Prefetch f+1's fragments
//  (linear over kw*KS+ks, staying in flight across staging barriers) breaks
//  the chain.
//  - conv1-3: banded-GEMM on v_mfma_f32_16x16x32_bf16 (R7-verified):
//    M=(ox,oy), N=co*16+oz, K=(ci,kx,ky)x(iz padded to ZPK), acc over kw.
//    B pre-packed in fragment order [kw][ks][nt][lane][8] (bf16 RNE).
//    A: one ds_read_b128 per fragment from ZS-strided LDS slab.
//    D: col=lane&15 (=oz), row=(lane>>4)*4+reg (=m).
//  - conv4/5 on the R3 f16 dot2 path; dense1/2 unchanged.
// ---------------------------------------------------------------------------

#define BATCH 256
typedef _Float16 half_t;
typedef _Float16 h2_t  __attribute__((ext_vector_type(2)));
typedef short    bf16x8 __attribute__((ext_vector_type(8)));
typedef float    f32x4 __attribute__((ext_vector_type(4)));
typedef unsigned int   uint32;
typedef unsigned short ushort16;

__device__ __forceinline__ float dot2f(uint32 a, uint32 b, float c) {
    return __builtin_amdgcn_fdot2(__builtin_bit_cast(h2_t, a),
                                  __builtin_bit_cast(h2_t, b), c, false);
}

// f32 -> bf16 bits, round-to-nearest-even (finite inputs only)
__device__ __forceinline__ ushort16 f2bf(float f) {
    const uint32 u = __builtin_bit_cast(uint32, f);
    return (ushort16)((u + 0x7FFFu + ((u >> 16) & 1u)) >> 16);
}

// ---- x pre-pass: fp32 [256*18][324][18] -> bf16 [256*18][324][24], pads 0
__global__ void cvt_x_pad(const float* __restrict__ x,
                          ushort16* __restrict__ xp) {
    constexpr int CH  = 972;               // uint4 chunks per (b,iw) slice
    constexpr int NSL = BATCH * 18;
    const int c = blockIdx.x * blockDim.x + threadIdx.x;
    if (c >= NSL * CH) return;
    const int s   = c / CH;
    const int j   = c - s * CH;            // chunk within slice: row r=j/3
    const int r   = j / 3;
    const int g   = j - 3 * r;             // z-phase: elems 8g..8g+8 of 24
    const float* src = x + ((size_t)s * 324 + r) * 18 + 8 * g;
    uint32 w[4];
    if (g < 2) {                           // z 0..15 all valid
        #pragma unroll
        for (int q = 0; q < 4; ++q) {
            const float2 v = ((const float2*)src)[q];   // 8B-aligned
            w[q] = (uint32)f2bf(v.x) | ((uint32)f2bf(v.y) << 16);
        }
    } else {                               // z 16,17 valid; 18..23 pad
        const float2 v = *(const float2*)src;
        w[0] = (uint32)f2bf(v.x) | ((uint32)f2bf(v.y) << 16);
        w[1] = w[2] = w[3] = 0;
    }
    ((uint4*)xp)[c] = (uint4){w[0], w[1], w[2], w[3]};
}

// ---- B-matrix pre-pack: fragment order [kw][ks][nt][lane][8], bf16 -------
template <int CIN, int COUT, int ISZ, int OSZ, int ZPK, int KS>
__device__ void pack_mfma_one(const float* __restrict__ w,
                              ushort16* __restrict__ Bq, int gtid, int gstride) {
    constexpr int TOT = 4 * KS * COUT * 512;   // 512 bf16 per fragment
    for (int t = gtid; t < TOT; t += gstride) {
        const int h  = t & 7;
        const int l  = (t >> 3) & 63;
        const int f  = t >> 9;                 // (kw*KS+ks)*COUT + nt
        const int nt = f % COUT;
        const int ks = (f / COUT) % KS;
        const int kw = f / (COUT * KS);
        const int k  = ks * 32 + (l >> 4) * 8 + h;
        const int combo = k / ZPK;
        const int iz = k - combo * ZPK;
        const int ci = combo >> 4;             // combo = (ci*4+kx)*4+ky
        const int kx = (combo >> 2) & 3;
        const int ky = combo & 3;
        const int oz = l & 15;
        const int kz = iz - oz;
        ushort16 v = 0;
        if (oz < OSZ && kz >= 0 && kz < 4 && iz < ISZ)
            v = f2bf(w[((((nt * CIN + ci) * 4 + kw) * 4 + kx) * 4 + ky) * 4 + kz]);
        Bq[t] = v;
    }
}

__global__ void pack_weights_mfma(const float* __restrict__ w1,
                                  const float* __restrict__ w2,
                                  const float* __restrict__ w3,
                                  ushort16* __restrict__ Bq1,
                                  ushort16* __restrict__ Bq2,
                                  ushort16* __restrict__ Bq3) {
    const int gtid = blockIdx.x * blockDim.x + threadIdx.x;
    const int gs   = gridDim.x * blockDim.x;
    pack_mfma_one<1, 3, 18, 15, 24, 12>(w1, Bq1, gtid, gs);
    pack_mfma_one<3, 3, 15, 12, 16, 24>(w2, Bq2, gtid, gs);
    pack_mfma_one<3, 4, 12,  9, 16, 24>(w3, Bq3, gtid, gs);
}

// ---------------------------------------------------------------------------
// MFMA conv (bf16): one (b,ow) slab per block; waves split M-tiles; each wave
// accumulates all COUT n-tiles.  Depth-1 register prefetch of B-fragments
// (linear over f = kw*KS+ks; loads stay in flight across staging barriers).
//  IN_MODE 0: fp32 natural rows stride ISZ (conv1 fallback)
//  IN_MODE 2: bf16 rows pre-padded to IPZ -> uint4 staging (identity if
//             IPZ==ZS, else row-restrided)
//  OUTF16: emit f16 bits; ZS: LDS row stride; OZS: output z stride.
// ---------------------------------------------------------------------------
template <int CIN, int COUT, int ISZ, int OSZ, int ZPK, int KS,
          int MT_TOT, int NT, int IN_MODE, bool OUTF16, int ZS, int IPZ, int OZS>
__global__ __launch_bounds__(NT)
void conv4d_mfma(const void* __restrict__ in_v,
                 const ushort16* __restrict__ Bq,
                 const float* __restrict__ bias,
                 ushort16* __restrict__ out) {
    constexpr int K   = 4;
    constexpr int R2  = ISZ * ISZ;
    constexpr int NW  = NT / 64;
    constexpr int MT_PER = (MT_TOT + NW - 1) / NW;
    constexpr int SLAB = (CIN * R2 + 24) * ZS;   // +24 rows OOB margin
    constexpr int FTOT = K * KS;                 // total fragment steps
    static_assert(CIN * 16 * ZPK == KS * 32, "K-dim bookkeeping");
    static_assert(ZPK % 8 == 0, "8-slice must not straddle combos");
    static_assert(ZS >= ZPK && IPZ >= ZPK, "strides must cover logical K rows");

    __shared__ ushort16 slab[SLAB];

    const int tid = threadIdx.x;
    const int l   = tid & 63;
    const int wv  = tid >> 6;
    const int b   = blockIdx.x / OSZ;
    const int ow  = blockIdx.x % OSZ;
    const int lg  = l >> 4;

    // NaN hardening: pads (beyond valid z) and OOB margin must be finite.
    for (int t = tid; t < SLAB; t += NT) slab[t] = 0;

    // per-lane A-row base per owned M-tile
    int mbase[MT_PER];
    #pragma unroll
    for (int i = 0; i < MT_PER; ++i) {
        const int mt = wv + NW * i;
        const int m  = (mt < MT_TOT) ? (mt * 16 + (l & 15)) : 0;
        mbase[i] = (m / OSZ) * ISZ + (m % OSZ);
    }

    f32x4 acc[MT_PER][COUT];
    #pragma unroll
    for (int i = 0; i < MT_PER; ++i)
        #pragma unroll
        for (int nt = 0; nt < COUT; ++nt)
            acc[i][nt] = (f32x4){0.f, 0.f, 0.f, 0.f};

    // prime the fragment pipeline: f = 0
    bf16x8 bqc[COUT], bqn[COUT];
    {
        const ushort16* bp = Bq + (size_t)l * 8;
        #pragma unroll
        for (int nt = 0; nt < COUT; ++nt)
            bqc[nt] = *(const bf16x8*)(bp + nt * 512);
    }

    for (int kw = 0; kw < K; ++kw) {
        __syncthreads();                       // readers of previous slab done
        const int iw = ow + kw;
        if constexpr (IN_MODE == 0) {
            // fp32 natural, CIN==1; float2 -> packed bf16 pairs
            const float* g = (const float*)in_v +
                ((size_t)b * ISZ + iw) * (size_t)(R2 * ISZ);
            for (int t = tid; t < (R2 * ISZ) / 2; t += NT) {
                const float2 v = ((const float2*)g)[t];
                const int e = 2 * t;
                const int r = e / ISZ, z = e % ISZ;    // ISZ even: no straddle
                const uint32 pv = (uint32)f2bf(v.x) | ((uint32)f2bf(v.y) << 16);
                *(uint32*)&slab[r * ZS + z] = pv;
            }
        } else {
            constexpr int CPR = IPZ / 8;       // uint4 chunks per padded row
            constexpr int NCH = CIN * R2 * CPR;
            const ushort16* inp = (const ushort16*)in_v;
            for (int t = tid; t < NCH; t += NT) {
                const int ci  = t / (R2 * CPR);
                const int rem = t % (R2 * CPR);
                const uint4* g = (const uint4*)(inp +
                    ((size_t)(b * CIN + ci) * ISZ + iw) * (size_t)(R2 * IPZ));
                const uint4 v = g[rem];
                int dst;
                if constexpr (IPZ == ZS) {
                    dst = (ci * R2) * ZS + rem * 8;
                } else {
                    const int r = rem / CPR, c = rem % CPR;
                    dst = (ci * R2 + r) * ZS + c * 8;
                }
                *(uint4*)&slab[dst] = v;
            }
        }
        __syncthreads();

        #pragma unroll 2
        for (int ks = 0; ks < KS; ++ks) {
            const int f = kw * KS + ks;
            // prefetch next fragment set (stays in flight across barriers)
            if (f + 1 < FTOT) {
                const ushort16* bp = Bq + (size_t)(f + 1) * COUT * 512 + l * 8;
                #pragma unroll
                for (int nt = 0; nt < COUT; ++nt)
                    bqn[nt] = *(const bf16x8*)(bp + nt * 512);
            }
            // A fragment address parts (per-lane)
            const int k8    = ks * 32 + lg * 8;
            const int combo = k8 / ZPK;
            const int iz0   = k8 - combo * ZPK;
            const int ci    = combo >> 4;
            const int kx    = (combo >> 2) & 3;
            const int ky    = combo & 3;
            const int roff  = ci * R2 + kx * ISZ + ky;
            #pragma unroll
            for (int i = 0; i < MT_PER; ++i) {
                if (wv + NW * i < MT_TOT) {
                    const bf16x8 a =
                        *(const bf16x8*)&slab[(mbase[i] + roff) * ZS + iz0];
                    #pragma unroll
                    for (int nt = 0; nt < COUT; ++nt)
                        acc[i][nt] = __builtin_amdgcn_mfma_f32_16x16x32_bf16(
                            a, bqc[nt], acc[i][nt], 0, 0, 0);
                }
            }
            #pragma unroll
            for (int nt = 0; nt < COUT; ++nt) bqc[nt] = bqn[nt];
        }
    }

    // ---- epilogue: D col = lane&15 (= oz), row = (lane>>4)*4 + reg (= m)
    const int oz = l & 15;
    #pragma unroll
    for (int i = 0; i < MT_PER; ++i) {
        const int mt = wv + NW * i;
        if (mt < MT_TOT && oz < OZS) {
            #pragma unroll
            for (int nt = 0; nt < COUT; ++nt) {
                const float bv = bias[nt];
                #pragma unroll
                for (int r = 0; r < 4; ++r) {
                    const int m = mt * 16 + (l >> 4) * 4 + r;
                    if (m < OSZ * OSZ) {
                        const int ox = m / OSZ, oy = m % OSZ;
                        const float vv = fmaxf(acc[i][nt][r] + bv, 0.f);
                        ushort16 bits;
                        if constexpr (OUTF16) {
                            const half_t hv = (half_t)vv;
                            bits = __builtin_bit_cast(ushort16, hv);
                        } else {
                            bits = f2bf(vv);
                        }
                        out[(((((size_t)b * COUT + nt) * OSZ + ow) * OSZ + ox)
                             * OSZ + oy) * OZS + oz] = bits;
                    }
                }
            }
        }
    }
}

// ---------------------------------------------------------------------------
// R3 conv path (per-(co,ox,oy) lines, LDS weights, f16 dot2) — conv4/conv5.
// ---------------------------------------------------------------------------
template <int CIN, int COUT, int K, int ISZ, int OSZ,
          int IPG, int OPG, int ZP, int NT, bool INF32>
__global__ __launch_bounds__(NT)
void conv4d_relu_f16(const void* __restrict__ in_v,
                     const float* __restrict__ w,
                     const float* __restrict__ bias,
                     half_t* __restrict__ out) {
    constexpr int KP  = 4;
    constexpr int R2  = ISZ * ISZ;
    constexpr int WTOT = CIN * K * K * K * COUT * KP;
    constexpr int LINES = COUT * OSZ * OSZ;
    constexpr int NIT = (LINES + NT - 1) / NT;
    constexpr int RL  = OSZ + KP - 1;
    constexpr int RQ  = (RL + 7) / 8;
    constexpr int NW  = RQ * 4;
    constexpr int NODD = (OSZ + 2) / 2;

    static_assert(8 * RQ <= ZP, "row read overruns z-pad");
    static_assert(NODD + 1 <= NW, "perm source word out of range");

    __shared__ half_t sw[WTOT];
    __shared__ half_t slab[CIN * R2 * ZP];

    const int tid = threadIdx.x;
    const int b   = blockIdx.x / OSZ;
    const int ow  = blockIdx.x % OSZ;

    for (int t = tid; t < WTOT; t += NT) {
        const int kz = t % KP; int c = t / KP;
        const int co = c % COUT; c /= COUT;
        const int ky = c % K; c /= K;
        const int kx = c % K; c /= K;
        const int kw = c % K; const int ci = c / K;
        const float v = (kz < K)
            ? w[((((co * CIN + ci) * K + kw) * K + kx) * K + ky) * K + kz]
            : 0.0f;
        sw[t] = (half_t)v;
    }

    float acc[NIT][OSZ];
    #pragma unroll
    for (int it = 0; it < NIT; ++it) {
        const int line = tid + it * NT;
        const float bv = (line < LINES) ? bias[line % COUT] : 0.0f;
        #pragma unroll
        for (int oz = 0; oz < OSZ; ++oz) acc[it][oz] = bv;
    }

    for (int kw = 0; kw < K; ++kw) {
        __syncthreads();
        const int iw = ow + kw;
        if constexpr (INF32) {
            const float* g = (const float*)in_v + ((size_t)b * ISZ + iw) * (size_t)(R2 * ISZ);
            for (int t = tid; t < R2 * ISZ; t += NT) {
                const int r = t / ISZ, z = t % ISZ;
                slab[r * ZP + z] = (half_t)g[t];
            }
        } else {
            constexpr int CPR = IPG / 8;
            constexpr int NCH = CIN * R2 * CPR;
            const half_t* inp = (const half_t*)in_v;
            for (int t = tid; t < NCH; t += NT) {
                const int ci  = t / (R2 * CPR);
                const int rem = t % (R2 * CPR);
                const int r = rem / CPR, c = rem % CPR;
                const uint4* g = (const uint4*)(inp +
                    ((size_t)(b * CIN + ci) * ISZ + iw) * (size_t)(R2 * IPG));
                const uint4 v = g[rem];
                *(uint4*)&slab[(ci * R2 + r) * ZP + 8 * c] = v;
            }
        }
        __syncthreads();

        #pragma unroll
        for (int it = 0; it < NIT; ++it) {
            const int line = tid + it * NT;
            if (line >= LINES) continue;
            const int co = line % COUT;
            const int xy = line / COUT;
            const int ox = xy / OSZ;
            const int oy = xy % OSZ;
            #pragma unroll 1
            for (int ci = 0; ci < CIN; ++ci) {
                #pragma unroll 1
                for (int kx = 0; kx < K; ++kx) {
                    #pragma unroll
                    for (int ky = 0; ky < K; ++ky) {
                        const half_t* rp = &slab[((ci * ISZ + ox + kx) * ISZ + oy + ky) * ZP];
                        uint32 wd[NW];
                        #pragma unroll
                        for (int q = 0; q < RQ; ++q) {
                            const uint4 v = ((const uint4*)rp)[q];
                            wd[4*q+0] = v.x; wd[4*q+1] = v.y;
                            wd[4*q+2] = v.z; wd[4*q+3] = v.w;
                        }
                        uint32 od[NODD];
                        #pragma unroll
                        for (int i = 0; i < NODD; ++i)
                            od[i] = __builtin_amdgcn_perm(wd[i + 1], wd[i], 0x05040302u);
                        const int wb = ((((ci * K + kw) * K + kx) * K + ky) * COUT + co) * KP;
                        const uint2 wv = *(const uint2*)&sw[wb];
                        #pragma unroll
                        for (int oz = 0; oz < OSZ; ++oz) {
                            const int s1 = oz + 2;
                            const uint32 p0 = (oz & 1) ? od[oz >> 1] : wd[oz >> 1];
                            const uint32 p1 = (s1 & 1) ? od[s1 >> 1] : wd[s1 >> 1];
                            acc[it][oz] = dot2f(p0, wv.x, dot2f(p1, wv.y, acc[it][oz]));
                        }
                    }
                }
            }
        }
    }

    #pragma unroll
    for (int it = 0; it < NIT; ++it) {
        const int line = tid + it * NT;
        if (line >= LINES) continue;
        const int co = line % COUT;
        const int xy = line / COUT;
        const int ox = xy / OSZ;
        const int oy = xy % OSZ;
        half_t* op = out + (((((size_t)b * COUT + co) * OSZ + ow) * OSZ + ox) * OSZ + oy) * OPG;
        #pragma unroll
        for (int p = 0; p < OSZ / 2; ++p) {
            h2_t pv = { (half_t)fmaxf(acc[it][2*p],     0.0f),
                        (half_t)fmaxf(acc[it][2*p + 1], 0.0f) };
            ((uint32*)op)[p] = __builtin_bit_cast(uint32, pv);
        }
        if constexpr (OSZ & 1)
            op[OSZ - 1] = (half_t)fmaxf(acc[it][OSZ - 1], 0.0f);
    }
}

// dense1: out[b,j] = relu(sum_k h[b,k]*w[j,k] + bias[j]); h f16 [256,1280]
__global__ void dense1_relu_f16(const half_t* __restrict__ h,
                                const float* __restrict__ w,
                                const float* __restrict__ bias,
                                float* __restrict__ out) {
    int idx = blockIdx.x * blockDim.x + threadIdx.x;
    if (idx >= BATCH * 33) return;
    const int j = idx % 33;
    const int i = idx / 33;
    const half_t* hr = h + (size_t)i * 1280;
    const float*  wr = w + (size_t)j * 1280;
    float a0 = bias[j], a1 = 0.f, a2 = 0.f, a3 = 0.f;
    for (int k = 0; k < 1280; k += 4) {
        a0 = fmaf((float)hr[k + 0], wr[k + 0], a0);
        a1 = fmaf((float)hr[k + 1], wr[k + 1], a1);
        a2 = fmaf((float)hr[k + 2], wr[k + 2], a2);
        a3 = fmaf((float)hr[k + 3], wr[k + 3], a3);
    }
    out[idx] = fmaxf((a0 + a1) + (a2 + a3), 0.0f);
}

// dense2 + softmax over 2 classes. h:[256,33] fp32, w:[2,33], out:[256,2]
__global__ void dense2_softmax(const float* __restrict__ h,
                               const float* __restrict__ w,
                               const float* __restrict__ bias,
                               float* __restrict__ out) {
    int i = blockIdx.x * blockDim.x + threadIdx.x;
    if (i >= BATCH) return;
    const float* hr = h + (size_t)i * 33;
    float a0 = bias[0], a1 = bias[1];
    for (int k = 0; k < 33; ++k) {
        a0 = fmaf(hr[k], w[k], a0);
        a1 = fmaf(hr[k], w[33 + k], a1);
    }
    const float m = fmaxf(a0, a1);
    const float e0 = expf(a0 - m);
    const float e1 = expf(a1 - m);
    const float s = e0 + e1;
    out[i * 2 + 0] = e0 / s;
    out[i * 2 + 1] = e1 / s;
}

extern "C" void kernel_launch(void* const* d_in, const int* in_sizes, int n_in,
                              void* d_out, int out_size, void* d_ws, size_t ws_size,
                              hipStream_t stream) {
    const float* x   = (const float*)d_in[0];
    const float* w1  = (const float*)d_in[1];
    const float* b1  = (const float*)d_in[2];
    const float* w2  = (const float*)d_in[3];
    const float* b2  = (const float*)d_in[4];
    const float* w3  = (const float*)d_in[5];
    const float* b3  = (const float*)d_in[6];
    const float* w4  = (const float*)d_in[7];
    const float* b4  = (const float*)d_in[8];
    const float* w5  = (const float*)d_in[9];
    const float* b5  = (const float*)d_in[10];
    const float* dw1 = (const float*)d_in[11];
    const float* db1 = (const float*)d_in[12];
    const float* dw2 = (const float*)d_in[13];
    const float* db2 = (const float*)d_in[14];

    // Workspace (16-bit units). Region A at 0, region B at 42M (84 MB).
    //  A: h1 bf16 41.472M / h3(f16 z16) / h5(f16); Bq1..Bq3 at A+41.5M
    //  B: xp bf16 35.83M (dead after conv1) / h2 bf16 21.23M / h4(f16 z8)
    //     / h6(fp32 at +8M ushort16-units)
    ushort16* wsA = (ushort16*)d_ws;
    ushort16* wsB = wsA + 42000000;

    ushort16* h1 = wsA;               // bf16, padded z=16
    ushort16* xp = wsB;               // bf16, padded z=24 (35,831,808)
    ushort16* h2 = wsB;               // bf16, padded z=16 (after xp dead)
    ushort16* h3 = wsA;               // f16 bits, padded z=16
    half_t*   h4 = (half_t*)wsB;      // f16, padded z=8
    half_t*   h5 = (half_t*)wsA;      // f16, natural [256][1280]
    float*    h6 = (float*)(wsB + 8000000);
    ushort16* Bq1 = wsA + 41500000;   // 4*12*3*512 = 73,728
    ushort16* Bq2 = wsA + 41600000;   // 4*24*3*512 = 147,456
    ushort16* Bq3 = wsA + 41760000;   // 4*24*4*512 = 196,608
    float* outp = (float*)d_out;

    // primary layout needs (42,000,000 + 35,831,808) * 2 bytes
    const bool big_ws = ws_size >= (size_t)155663616ull;

    // weight fragment pre-pack for conv1-3
    hipLaunchKernelGGL(pack_weights_mfma, dim3(64), dim3(256), 0, stream,
                       w1, w2, w3, Bq1, Bq2, Bq3);

    if (big_ws) {
        // x fp32 -> bf16 pre-padded [b][iw][324][24]
        constexpr int NCH = BATCH * 18 * 972;
        hipLaunchKernelGGL(cvt_x_pad, dim3((NCH + 255) / 256), dim3(256),
                           0, stream, x, xp);
        // conv1 from xp: identity-copy staging (IN_MODE 2, IPZ==ZS==24)
        hipLaunchKernelGGL((conv4d_mfma<1, 3, 18, 15, 24, 12, 15, 256, 2, false, 24, 24, 16>),
                           dim3(BATCH * 15), dim3(256), 0, stream, xp, Bq1, b1, h1);
    } else {
        // fallback: fp32 staging (IN_MODE 0)
        hipLaunchKernelGGL((conv4d_mfma<1, 3, 18, 15, 24, 12, 15, 256, 0, false, 24, 24, 16>),
                           dim3(BATCH * 15), dim3(256), 0, stream, x, Bq1, b1, h1);
    }
    // conv2: h1 -> h2 (bf16).  M=144 (9 Mt), ZPK=ZS=16, KS=24, 4 waves.
    hipLaunchKernelGGL((conv4d_mfma<3, 3, 15, 12, 16, 24, 9, 256, 2, false, 16, 16, 16>),
                       dim3(BATCH * 12), dim3(256), 0, stream, h1, Bq2, b2, h2);
    // conv3: h2 -> h3 (f16 out for conv4).  M=81 (6 Mt), ZPK=ZS=16, KS=24.
    hipLaunchKernelGGL((conv4d_mfma<3, 4, 12, 9, 16, 24, 6, 256, 2, true, 16, 16, 16>),
                       dim3(BATCH * 9), dim3(256), 0, stream, h2, Bq3, b3, h3);
    // conv4: h3 -> h4;  R3 f16 dot2 path
    hipLaunchKernelGGL((conv4d_relu_f16<4, 5, 4, 9, 6, 16, 8, 24, 192, false>),
                       dim3(BATCH * 6), dim3(192), 0, stream, h3, w4, b4, h4);
    // conv5: h4 -> h5 (natural, z=4);  R3 f16 dot2 path
    hipLaunchKernelGGL((conv4d_relu_f16<5, 5, 3, 6, 4, 8, 4, 8, 128, false>),
                       dim3(BATCH * 4), dim3(128), 0, stream, h4, w5, b5, h5);
    {   // dense1
        dim3 grid((BATCH * 33 + 255) / 256);
        hipLaunchKernelGGL(dense1_relu_f16, grid, dim3(256), 0, stream, h5, dw1, db1, h6);
    }
    {   // dense2 + softmax
        hipLaunchKernelGGL(dense2_softmax, dim3(1), dim3(256), 0, stream,
                           h6, dw2, db2, outp);
    }
}

// Round 12
// 718.194 us; speedup vs baseline: 1.1520x; 1.0014x over previous
//
#include <hip/hip_runtime.h>
#include <hip/hip_bf16.h>
#include <math.h>

// ---------------------------------------------------------------------------
// 5x conv4d(valid)+relu -> flatten -> dense(1280->33)+relu -> dense(33->2)
// -> softmax.  B=256.
//
// R12: R11 + XOR bank swizzle on the ZS=16 LDS slabs (conv2/conv3).
//  R11 model: conv2 is LDS-pipe-bound (A-read demand ~347 cyc/CU-epoch vs
//  MFMA 163); ds_read_b128 at 32B row stride = 4-way bank-group conflict
//  (1.06e7/dispatch, ~8->12 cyc per read).  Swizzle in 16B-chunk units:
//  chunk = row*2 + half; chunk ^= (row>>2)&7  -- mixes the half-bit with
//  row bit2 (odd groups get used) and row bits 3-4 into group bits.
//  4-way -> mostly <=3/2-way (2-way free, m136).  Same involution applied
//  on staging write (dst=(t^((t>>3)&7))*8) and A-read; bijective per octet;
//  conv1 (ZS=24, 48B stride) untouched.
//  - conv1-3: banded-GEMM on v_mfma_f32_16x16x32_bf16 + depth-1 B-fragment
//    register prefetch (R11): M=(ox,oy), N=co*16+oz, K=(ci,kx,ky)x(iz pad
//    ZPK), acc over kw.  B pre-packed [kw][ks][nt][lane][8] (bf16 RNE).
//    D: col=lane&15 (=oz), row=(lane>>4)*4+reg (=m).
//  - conv4/5 on the R3 f16 dot2 path; dense1/2 unchanged.
// ---------------------------------------------------------------------------

#define BATCH 256
typedef _Float16 half_t;
typedef _Float16 h2_t  __attribute__((ext_vector_type(2)));
typedef short    bf16x8 __attribute__((ext_vector_type(8)));
typedef float    f32x4 __attribute__((ext_vector_type(4)));
typedef unsigned int   uint32;
typedef unsigned short ushort16;

__device__ __forceinline__ float dot2f(uint32 a, uint32 b, float c) {
    return __builtin_amdgcn_fdot2(__builtin_bit_cast(h2_t, a),
                                  __builtin_bit_cast(h2_t, b), c, false);
}

// f32 -> bf16 bits, round-to-nearest-even (finite inputs only)
__device__ __forceinline__ ushort16 f2bf(float f) {
    const uint32 u = __builtin_bit_cast(uint32, f);
    return (ushort16)((u + 0x7FFFu + ((u >> 16) & 1u)) >> 16);
}

// ---- x pre-pass: fp32 [256*18][324][18] -> bf16 [256*18][324][24], pads 0
__global__ void cvt_x_pad(const float* __restrict__ x,
                          ushort16* __restrict__ xp) {
    constexpr int CH  = 972;               // uint4 chunks per (b,iw) slice
    constexpr int NSL = BATCH * 18;
    const int c = blockIdx.x * blockDim.x + threadIdx.x;
    if (c >= NSL * CH) return;
    const int s   = c / CH;
    const int j   = c - s * CH;            // chunk within slice: row r=j/3
    const int r   = j / 3;
    const int g   = j - 3 * r;             // z-phase: elems 8g..8g+8 of 24
    const float* src = x + ((size_t)s * 324 + r) * 18 + 8 * g;
    uint32 w[4];
    if (g < 2) {                           // z 0..15 all valid
        #pragma unroll
        for (int q = 0; q < 4; ++q) {
            const float2 v = ((const float2*)src)[q];   // 8B-aligned
            w[q] = (uint32)f2bf(v.x) | ((uint32)f2bf(v.y) << 16);
        }
    } else {                               // z 16,17 valid; 18..23 pad
        const float2 v = *(const float2*)src;
        w[0] = (uint32)f2bf(v.x) | ((uint32)f2bf(v.y) << 16);
        w[1] = w[2] = w[3] = 0;
    }
    ((uint4*)xp)[c] = (uint4){w[0], w[1], w[2], w[3]};
}

// ---- B-matrix pre-pack: fragment order [kw][ks][nt][lane][8], bf16 -------
template <int CIN, int COUT, int ISZ, int OSZ, int ZPK, int KS>
__device__ void pack_mfma_one(const float* __restrict__ w,
                              ushort16* __restrict__ Bq, int gtid, int gstride) {
    constexpr int TOT = 4 * KS * COUT * 512;   // 512 bf16 per fragment
    for (int t = gtid; t < TOT; t += gstride) {
        const int h  = t & 7;
        const int l  = (t >> 3) & 63;
        const int f  = t >> 9;                 // (kw*KS+ks)*COUT + nt
        const int nt = f % COUT;
        const int ks = (f / COUT) % KS;
        const int kw = f / (COUT * KS);
        const int k  = ks * 32 + (l >> 4) * 8 + h;
        const int combo = k / ZPK;
        const int iz = k - combo * ZPK;
        const int ci = combo >> 4;             // combo = (ci*4+kx)*4+ky
        const int kx = (combo >> 2) & 3;
        const int ky = combo & 3;
        const int oz = l & 15;
        const int kz = iz - oz;
        ushort16 v = 0;
        if (oz < OSZ && kz >= 0 && kz < 4 && iz < ISZ)
            v = f2bf(w[((((nt * CIN + ci) * 4 + kw) * 4 + kx) * 4 + ky) * 4 + kz]);
        Bq[t] = v;
    }
}

__global__ void pack_weights_mfma(const float* __restrict__ w1,
                                  const float* __restrict__ w2,
                                  const float* __restrict__ w3,
                                  ushort16* __restrict__ Bq1,
                                  ushort16* __restrict__ Bq2,
                                  ushort16* __restrict__ Bq3) {
    const int gtid = blockIdx.x * blockDim.x + threadIdx.x;
    const int gs   = gridDim.x * blockDim.x;
    pack_mfma_one<1, 3, 18, 15, 24, 12>(w1, Bq1, gtid, gs);
    pack_mfma_one<3, 3, 15, 12, 16, 24>(w2, Bq2, gtid, gs);
    pack_mfma_one<3, 4, 12,  9, 16, 24>(w3, Bq3, gtid, gs);
}

// ---------------------------------------------------------------------------
// MFMA conv (bf16): one (b,ow) slab per block; waves split M-tiles; each wave
// accumulates all COUT n-tiles.  Depth-1 register prefetch of B-fragments.
//  IN_MODE 0: fp32 natural rows stride ISZ (conv1 fallback)
//  IN_MODE 2: bf16 rows pre-padded to IPZ -> uint4 staging
//  OUTF16: emit f16 bits; ZS: LDS row stride; OZS: output z stride.
//  ZS==16 slabs get the XOR chunk swizzle (write+read same involution).
// ---------------------------------------------------------------------------
template <int CIN, int COUT, int ISZ, int OSZ, int ZPK, int KS,
          int MT_TOT, int NT, int IN_MODE, bool OUTF16, int ZS, int IPZ, int OZS>
__global__ __launch_bounds__(NT)
void conv4d_mfma(const void* __restrict__ in_v,
                 const ushort16* __restrict__ Bq,
                 const float* __restrict__ bias,
                 ushort16* __restrict__ out) {
    constexpr int K   = 4;
    constexpr int R2  = ISZ * ISZ;
    constexpr int NW  = NT / 64;
    constexpr int MT_PER = (MT_TOT + NW - 1) / NW;
    constexpr int SLAB = (CIN * R2 + 24) * ZS;   // +24 rows OOB margin
    constexpr int FTOT = K * KS;                 // total fragment steps
    constexpr bool SWZ = (ZS == 16) && (IN_MODE == 2) && (IPZ == ZS);
    static_assert(CIN * 16 * ZPK == KS * 32, "K-dim bookkeeping");
    static_assert(ZPK % 8 == 0, "8-slice must not straddle combos");
    static_assert(ZS >= ZPK && IPZ >= ZPK, "strides must cover logical K rows");

    __shared__ ushort16 slab[SLAB];

    const int tid = threadIdx.x;
    const int l   = tid & 63;
    const int wv  = tid >> 6;
    const int b   = blockIdx.x / OSZ;
    const int ow  = blockIdx.x % OSZ;
    const int lg  = l >> 4;

    // NaN hardening: pads (beyond valid z) and OOB margin must be finite.
    for (int t = tid; t < SLAB; t += NT) slab[t] = 0;

    // per-lane A-row base per owned M-tile
    int mbase[MT_PER];
    #pragma unroll
    for (int i = 0; i < MT_PER; ++i) {
        const int mt = wv + NW * i;
        const int m  = (mt < MT_TOT) ? (mt * 16 + (l & 15)) : 0;
        mbase[i] = (m / OSZ) * ISZ + (m % OSZ);
    }

    f32x4 acc[MT_PER][COUT];
    #pragma unroll
    for (int i = 0; i < MT_PER; ++i)
        #pragma unroll
        for (int nt = 0; nt < COUT; ++nt)
            acc[i][nt] = (f32x4){0.f, 0.f, 0.f, 0.f};

    // prime the fragment pipeline: f = 0
    bf16x8 bqc[COUT], bqn[COUT];
    {
        const ushort16* bp = Bq + (size_t)l * 8;
        #pragma unroll
        for (int nt = 0; nt < COUT; ++nt)
            bqc[nt] = *(const bf16x8*)(bp + nt * 512);
    }

    for (int kw = 0; kw < K; ++kw) {
        __syncthreads();                       // readers of previous slab done
        const int iw = ow + kw;
        if constexpr (IN_MODE == 0) {
            // fp32 natural, CIN==1; float2 -> packed bf16 pairs
            const float* g = (const float*)in_v +
                ((size_t)b * ISZ + iw) * (size_t)(R2 * ISZ);
            for (int t = tid; t < (R2 * ISZ) / 2; t += NT) {
                const float2 v = ((const float2*)g)[t];
                const int e = 2 * t;
                const int r = e / ISZ, z = e % ISZ;    // ISZ even: no straddle
                const uint32 pv = (uint32)f2bf(v.x) | ((uint32)f2bf(v.y) << 16);
                *(uint32*)&slab[r * ZS + z] = pv;
            }
        } else {
            constexpr int CPR = IPZ / 8;       // uint4 chunks per padded row
            constexpr int NCH = CIN * R2 * CPR;
            const ushort16* inp = (const ushort16*)in_v;
            for (int t = tid; t < NCH; t += NT) {
                const int ci  = t / (R2 * CPR);
                const int rem = t % (R2 * CPR);
                const uint4* g = (const uint4*)(inp +
                    ((size_t)(b * CIN + ci) * ISZ + iw) * (size_t)(R2 * IPZ));
                const uint4 v = g[rem];
                int dst;
                if constexpr (SWZ) {
                    // chunk index == t (CPR==2); XOR involution
                    dst = (t ^ ((t >> 3) & 7)) * 8;
                } else if constexpr (IPZ == ZS) {
                    dst = (ci * R2) * ZS + rem * 8;
                } else {
                    const int r = rem / CPR, c = rem % CPR;
                    dst = (ci * R2 + r) * ZS + c * 8;
                }
                *(uint4*)&slab[dst] = v;
            }
        }
        __syncthreads();

        #pragma unroll 2
        for (int ks = 0; ks < KS; ++ks) {
            const int f = kw * KS + ks;
            // prefetch next fragment set (stays in flight across barriers)
            if (f + 1 < FTOT) {
                const ushort16* bp = Bq + (size_t)(f + 1) * COUT * 512 + l * 8;
                #pragma unroll
                for (int nt = 0; nt < COUT; ++nt)
                    bqn[nt] = *(const bf16x8*)(bp + nt * 512);
            }
            // A fragment address parts (per-lane)
            const int k8    = ks * 32 + lg * 8;
            const int combo = k8 / ZPK;
            const int iz0   = k8 - combo * ZPK;
            const int ci    = combo >> 4;
            const int kx    = (combo >> 2) & 3;
            const int ky    = combo & 3;
            const int roff  = ci * R2 + kx * ISZ + ky;
            #pragma unroll
            for (int i = 0; i < MT_PER; ++i) {
                if (wv + NW * i < MT_TOT) {
                    const int row = mbase[i] + roff;
                    int eoff;
                    if constexpr (SWZ) {
                        const int chunk = row * 2 + (iz0 >> 3);
                        eoff = (chunk ^ ((row >> 2) & 7)) * 8;
                    } else {
                        eoff = row * ZS + iz0;
                    }
                    const bf16x8 a = *(const bf16x8*)&slab[eoff];
                    #pragma unroll
                    for (int nt = 0; nt < COUT; ++nt)
                        acc[i][nt] = __builtin_amdgcn_mfma_f32_16x16x32_bf16(
                            a, bqc[nt], acc[i][nt], 0, 0, 0);
                }
            }
            #pragma unroll
            for (int nt = 0; nt < COUT; ++nt) bqc[nt] = bqn[nt];
        }
    }

    // ---- epilogue: D col = lane&15 (= oz), row = (lane>>4)*4 + reg (= m)
    const int oz = l & 15;
    #pragma unroll
    for (int i = 0; i < MT_PER; ++i) {
        const int mt = wv + NW * i;
        if (mt < MT_TOT && oz < OZS) {
            #pragma unroll
            for (int nt = 0; nt < COUT; ++nt) {
                const float bv = bias[nt];
                #pragma unroll
                for (int r = 0; r < 4; ++r) {
                    const int m = mt * 16 + (l >> 4) * 4 + r;
                    if (m < OSZ * OSZ) {
                        const int ox = m / OSZ, oy = m % OSZ;
                        const float vv = fmaxf(acc[i][nt][r] + bv, 0.f);
                        ushort16 bits;
                        if constexpr (OUTF16) {
                            const half_t hv = (half_t)vv;
                            bits = __builtin_bit_cast(ushort16, hv);
                        } else {
                            bits = f2bf(vv);
                        }
                        out[(((((size_t)b * COUT + nt) * OSZ + ow) * OSZ + ox)
                             * OSZ + oy) * OZS + oz] = bits;
                    }
                }
            }
        }
    }
}

// ---------------------------------------------------------------------------
// R3 conv path (per-(co,ox,oy) lines, LDS weights, f16 dot2) — conv4/conv5.
// ---------------------------------------------------------------------------
template <int CIN, int COUT, int K, int ISZ, int OSZ,
          int IPG, int OPG, int ZP, int NT, bool INF32>
__global__ __launch_bounds__(NT)
void conv4d_relu_f16(const void* __restrict__ in_v,
                     const float* __restrict__ w,
                     const float* __restrict__ bias,
                     half_t* __restrict__ out) {
    constexpr int KP  = 4;
    constexpr int R2  = ISZ * ISZ;
    constexpr int WTOT = CIN * K * K * K * COUT * KP;
    constexpr int LINES = COUT * OSZ * OSZ;
    constexpr int NIT = (LINES + NT - 1) / NT;
    constexpr int RL  = OSZ + KP - 1;
    constexpr int RQ  = (RL + 7) / 8;
    constexpr int NW  = RQ * 4;
    constexpr int NODD = (OSZ + 2) / 2;

    static_assert(8 * RQ <= ZP, "row read overruns z-pad");
    static_assert(NODD + 1 <= NW, "perm source word out of range");

    __shared__ half_t sw[WTOT];
    __shared__ half_t slab[CIN * R2 * ZP];

    const int tid = threadIdx.x;
    const int b   = blockIdx.x / OSZ;
    const int ow  = blockIdx.x % OSZ;

    for (int t = tid; t < WTOT; t += NT) {
        const int kz = t % KP; int c = t / KP;
        const int co = c % COUT; c /= COUT;
        const int ky = c % K; c /= K;
        const int kx = c % K; c /= K;
        const int kw = c % K; const int ci = c / K;
        const float v = (kz < K)
            ? w[((((co * CIN + ci) * K + kw) * K + kx) * K + ky) * K + kz]
            : 0.0f;
        sw[t] = (half_t)v;
    }

    float acc[NIT][OSZ];
    #pragma unroll
    for (int it = 0; it < NIT; ++it) {
        const int line = tid + it * NT;
        const float bv = (line < LINES) ? bias[line % COUT] : 0.0f;
        #pragma unroll
        for (int oz = 0; oz < OSZ; ++oz) acc[it][oz] = bv;
    }

    for (int kw = 0; kw < K; ++kw) {
        __syncthreads();
        const int iw = ow + kw;
        if constexpr (INF32) {
            const float* g = (const float*)in_v + ((size_t)b * ISZ + iw) * (size_t)(R2 * ISZ);
            for (int t = tid; t < R2 * ISZ; t += NT) {
                const int r = t / ISZ, z = t % ISZ;
                slab[r * ZP + z] = (half_t)g[t];
            }
        } else {
            constexpr int CPR = IPG / 8;
            constexpr int NCH = CIN * R2 * CPR;
            const half_t* inp = (const half_t*)in_v;
            for (int t = tid; t < NCH; t += NT) {
                const int ci  = t / (R2 * CPR);
                const int rem = t % (R2 * CPR);
                const int r = rem / CPR, c = rem % CPR;
                const uint4* g = (const uint4*)(inp +
                    ((size_t)(b * CIN + ci) * ISZ + iw) * (size_t)(R2 * IPG));
                const uint4 v = g[rem];
                *(uint4*)&slab[(ci * R2 + r) * ZP + 8 * c] = v;
            }
        }
        __syncthreads();

        #pragma unroll
        for (int it = 0; it < NIT; ++it) {
            const int line = tid + it * NT;
            if (line >= LINES) continue;
            const int co = line % COUT;
            const int xy = line / COUT;
            const int ox = xy / OSZ;
            const int oy = xy % OSZ;
            #pragma unroll 1
            for (int ci = 0; ci < CIN; ++ci) {
                #pragma unroll 1
                for (int kx = 0; kx < K; ++kx) {
                    #pragma unroll
                    for (int ky = 0; ky < K; ++ky) {
                        const half_t* rp = &slab[((ci * ISZ + ox + kx) * ISZ + oy + ky) * ZP];
                        uint32 wd[NW];
                        #pragma unroll
                        for (int q = 0; q < RQ; ++q) {
                            const uint4 v = ((const uint4*)rp)[q];
                            wd[4*q+0] = v.x; wd[4*q+1] = v.y;
                            wd[4*q+2] = v.z; wd[4*q+3] = v.w;
                        }
                        uint32 od[NODD];
                        #pragma unroll
                        for (int i = 0; i < NODD; ++i)
                            od[i] = __builtin_amdgcn_perm(wd[i + 1], wd[i], 0x05040302u);
                        const int wb = ((((ci * K + kw) * K + kx) * K + ky) * COUT + co) * KP;
                        const uint2 wv = *(const uint2*)&sw[wb];
                        #pragma unroll
                        for (int oz = 0; oz < OSZ; ++oz) {
                            const int s1 = oz + 2;
                            const uint32 p0 = (oz & 1) ? od[oz >> 1] : wd[oz >> 1];
                            const uint32 p1 = (s1 & 1) ? od[s1 >> 1] : wd[s1 >> 1];
                            acc[it][oz] = dot2f(p0, wv.x, dot2f(p1, wv.y, acc[it][oz]));
                        }
                    }
                }
            }
        }
    }

    #pragma unroll
    for (int it = 0; it < NIT; ++it) {
        const int line = tid + it * NT;
        if (line >= LINES) continue;
        const int co = line % COUT;
        const int xy = line / COUT;
        const int ox = xy / OSZ;
        const int oy = xy % OSZ;
        half_t* op = out + (((((size_t)b * COUT + co) * OSZ + ow) * OSZ + ox) * OSZ + oy) * OPG;
        #pragma unroll
        for (int p = 0; p < OSZ / 2; ++p) {
            h2_t pv = { (half_t)fmaxf(acc[it][2*p],     0.0f),
                        (half_t)fmaxf(acc[it][2*p + 1], 0.0f) };
            ((uint32*)op)[p] = __builtin_bit_cast(uint32, pv);
        }
        if constexpr (OSZ & 1)
            op[OSZ - 1] = (half_t)fmaxf(acc[it][OSZ - 1], 0.0f);
    }
}

// dense1: out[b,j] = relu(sum_k h[b,k]*w[j,k] + bias[j]); h f16 [256,1280]
__global__ void dense1_relu_f16(const half_t* __restrict__ h,
                                const float* __restrict__ w,
                                const float* __restrict__ bias,
                                float* __restrict__ out) {
    int idx = blockIdx.x * blockDim.x + threadIdx.x;
    if (idx >= BATCH * 33) return;
    const int j = idx % 33;
    const int i = idx / 33;
    const half_t* hr = h + (size_t)i * 1280;
    const float*  wr = w + (size_t)j * 1280;
    float a0 = bias[j], a1 = 0.f, a2 = 0.f, a3 = 0.f;
    for (int k = 0; k < 1280; k += 4) {
        a0 = fmaf((float)hr[k + 0], wr[k + 0], a0);
        a1 = fmaf((float)hr[k + 1], wr[k + 1], a1);
        a2 = fmaf((float)hr[k + 2], wr[k + 2], a2);
        a3 = fmaf((float)hr[k + 3], wr[k + 3], a3);
    }
    out[idx] = fmaxf((a0 + a1) + (a2 + a3), 0.0f);
}

// dense2 + softmax over 2 classes. h:[256,33] fp32, w:[2,33], out:[256,2]
__global__ void dense2_softmax(const float* __restrict__ h,
                               const float* __restrict__ w,
                               const float* __restrict__ bias,
                               float* __restrict__ out) {
    int i = blockIdx.x * blockDim.x + threadIdx.x;
    if (i >= BATCH) return;
    const float* hr = h + (size_t)i * 33;
    float a0 = bias[0], a1 = bias[1];
    for (int k = 0; k < 33; ++k) {
        a0 = fmaf(hr[k], w[k], a0);
        a1 = fmaf(hr[k], w[33 + k], a1);
    }
    const float m = fmaxf(a0, a1);
    const float e0 = expf(a0 - m);
    const float e1 = expf(a1 - m);
    const float s = e0 + e1;
    out[i * 2 + 0] = e0 / s;
    out[i * 2 + 1] = e1 / s;
}

extern "C" void kernel_launch(void* const* d_in, const int* in_sizes, int n_in,
                              void* d_out, int out_size, void* d_ws, size_t ws_size,
                              hipStream_t stream) {
    const float* x   = (const float*)d_in[0];
    const float* w1  = (const float*)d_in[1];
    const float* b1  = (const float*)d_in[2];
    const float* w2  = (const float*)d_in[3];
    const float* b2  = (const float*)d_in[4];
    const float* w3  = (const float*)d_in[5];
    const float* b3  = (const float*)d_in[6];
    const float* w4  = (const float*)d_in[7];
    const float* b4  = (const float*)d_in[8];
    const float* w5  = (const float*)d_in[9];
    const float* b5  = (const float*)d_in[10];
    const float* dw1 = (const float*)d_in[11];
    const float* db1 = (const float*)d_in[12];
    const float* dw2 = (const float*)d_in[13];
    const float* db2 = (const float*)d_in[14];

    // Workspace (16-bit units). Region A at 0, region B at 42M (84 MB).
    //  A: h1 bf16 41.472M / h3(f16 z16) / h5(f16); Bq1..Bq3 at A+41.5M
    //  B: xp bf16 35.83M (dead after conv1) / h2 bf16 21.23M / h4(f16 z8)
    //     / h6(fp32 at +8M ushort16-units)
    ushort16* wsA = (ushort16*)d_ws;
    ushort16* wsB = wsA + 42000000;

    ushort16* h1 = wsA;               // bf16, padded z=16
    ushort16* xp = wsB;               // bf16, padded z=24 (35,831,808)
    ushort16* h2 = wsB;               // bf16, padded z=16 (after xp dead)
    ushort16* h3 = wsA;               // f16 bits, padded z=16
    half_t*   h4 = (half_t*)wsB;      // f16, padded z=8
    half_t*   h5 = (half_t*)wsA;      // f16, natural [256][1280]
    float*    h6 = (float*)(wsB + 8000000);
    ushort16* Bq1 = wsA + 41500000;   // 4*12*3*512 = 73,728
    ushort16* Bq2 = wsA + 41600000;   // 4*24*3*512 = 147,456
    ushort16* Bq3 = wsA + 41760000;   // 4*24*4*512 = 196,608
    float* outp = (float*)d_out;

    // primary layout needs (42,000,000 + 35,831,808) * 2 bytes
    const bool big_ws = ws_size >= (size_t)155663616ull;

    // weight fragment pre-pack for conv1-3
    hipLaunchKernelGGL(pack_weights_mfma, dim3(64), dim3(256), 0, stream,
                       w1, w2, w3, Bq1, Bq2, Bq3);

    if (big_ws) {
        // x fp32 -> bf16 pre-padded [b][iw][324][24]
        constexpr int NCH = BATCH * 18 * 972;
        hipLaunchKernelGGL(cvt_x_pad, dim3((NCH + 255) / 256), dim3(256),
                           0, stream, x, xp);
        // conv1 from xp: identity-copy staging (IN_MODE 2, IPZ==ZS==24)
        hipLaunchKernelGGL((conv4d_mfma<1, 3, 18, 15, 24, 12, 15, 256, 2, false, 24, 24, 16>),
                           dim3(BATCH * 15), dim3(256), 0, stream, xp, Bq1, b1, h1);
    } else {
        // fallback: fp32 staging (IN_MODE 0)
        hipLaunchKernelGGL((conv4d_mfma<1, 3, 18, 15, 24, 12, 15, 256, 0, false, 24, 24, 16>),
                           dim3(BATCH * 15), dim3(256), 0, stream, x, Bq1, b1, h1);
    }
    // conv2: h1 -> h2 (bf16).  M=144 (9 Mt), ZPK=ZS=16, KS=24, swizzled.
    hipLaunchKernelGGL((conv4d_mfma<3, 3, 15, 12, 16, 24, 9, 256, 2, false, 16, 16, 16>),
                       dim3(BATCH * 12), dim3(256), 0, stream, h1, Bq2, b2, h2);
    // conv3: h2 -> h3 (f16 out for conv4).  M=81 (6 Mt), swizzled.
    hipLaunchKernelGGL((conv4d_mfma<3, 4, 12, 9, 16, 24, 6, 256, 2, true, 16, 16, 16>),
                       dim3(BATCH * 9), dim3(256), 0, stream, h2, Bq3, b3, h3);
    // conv4: h3 -> h4;  R3 f16 dot2 path
    hipLaunchKernelGGL((conv4d_relu_f16<4, 5, 4, 9, 6, 16, 8, 24, 192, false>),
                       dim3(BATCH * 6), dim3(192), 0, stream, h3, w4, b4, h4);
    // conv5: h4 -> h5 (natural, z=4);  R3 f16 dot2 path
    hipLaunchKernelGGL((conv4d_relu_f16<5, 5, 3, 6, 4, 8, 4, 8, 128, false>),
                       dim3(BATCH * 4), dim3(128), 0, stream, h4, w5, b5, h5);
    {   // dense1
        dim3 grid((BATCH * 33 + 255) / 256);
        hipLaunchKernelGGL(dense1_relu_f16, grid, dim3(256), 0, stream, h5, dw1, db1, h6);
    }
    {   // dense2 + softmax
        hipLaunchKernelGGL(dense2_softmax, dim3(1), dim3(256), 0, stream,
                           h6, dw2, db2, outp);
    }
}